// Round 7
// baseline (1053.009 us; speedup 1.0000x reference)
//
#include <hip/hip_runtime.h>
#include <hip/hip_bf16.h>

typedef __bf16 bf16_t;
typedef bf16_t bf16x8 __attribute__((ext_vector_type(8)));
typedef float f32x4 __attribute__((ext_vector_type(4)));

#define TOK 8192          // B*S
#define DMODEL 2048
#define DINNER 4096
#define XBCN 4352         // conv dim = 34*128
#define DSTATE 128
#define NH 64
#define HD 64
#define NBC 64            // B * (S/CHUNK) = 2*32
#define WINT_ROWS 8448    // z (4096) + xbc (4352)

// async global->LDS, 16B per lane, LDS dest = wave-uniform base + lane*16
__device__ __forceinline__ void gld16(const bf16_t* g, bf16_t* l) {
  __builtin_amdgcn_global_load_lds((const __attribute__((address_space(1))) void*)g,
                                   (__attribute__((address_space(3))) void*)l, 16, 0, 0);
}

__device__ __forceinline__ f32x4 mfma16(bf16x8 a, bf16x8 b, f32x4 c) {
  return __builtin_amdgcn_mfma_f32_16x16x32_bf16(a, b, c, 0, 0, 0);
}

// opaque LDS read: compiler cannot link it to global_load_lds's LDS writes,
// so it emits NO vmcnt waits for it; we do our own counted vmcnt + lgkmcnt.
__device__ __forceinline__ bf16x8 ldsr(unsigned addr) {
  f32x4 r;
  asm volatile("ds_read_b128 %0, %1" : "=v"(r) : "v"(addr));
  return __builtin_bit_cast(bf16x8, r);
}

// ---------------- utility kernels ----------------

// hidden f32 -> hi (bf16) + lo (bf16 residual)
__global__ __launch_bounds__(256)
void cast_split_kernel(const float* __restrict__ in, bf16_t* __restrict__ hi,
                       bf16_t* __restrict__ lo, size_t n) {
  size_t i = ((size_t)blockIdx.x * 256 + threadIdx.x) * 8;
  if (i + 8 > n) return;
  float4 a = *(const float4*)(in + i);
  float4 b = *(const float4*)(in + i + 4);
  float v[8] = {a.x,a.y,a.z,a.w,b.x,b.y,b.z,b.w};
  bf16x8 h, l;
#pragma unroll
  for (int j = 0; j < 8; ++j) {
    h[j] = (bf16_t)v[j];
    l[j] = (bf16_t)(v[j] - (float)h[j]);
  }
  *(bf16x8*)(hi + i) = h;
  *(bf16x8*)(lo + i) = l;
}

// in: R x C f32 row-major -> out: outRows x R bf16 (out[c][r] = in[r][c])
__global__ __launch_bounds__(256)
void transpose_cast_kernel(const float* __restrict__ in, bf16_t* __restrict__ out,
                           int R, int C, int outRows) {
  __shared__ float tile[32][33];
  const int c0 = blockIdx.x * 32;
  const int r0 = blockIdx.y * 32;
  const int tx = threadIdx.x & 31;
  const int ty = threadIdx.x >> 5;
#pragma unroll
  for (int k = 0; k < 4; ++k) {
    int r = r0 + ty + k*8;
    int c = c0 + tx;
    tile[ty + k*8][tx] = (c < C) ? in[(size_t)r * C + c] : 0.f;
  }
  __syncthreads();
#pragma unroll
  for (int k = 0; k < 4; ++k) {
    int oc = c0 + ty + k*8;
    int orr = r0 + tx;
    out[(size_t)oc * R + orr] = (bf16_t)tile[tx][ty + k*8];
  }
}

// W_in dt columns -> Whi/Wlo [64][2048] bf16 split
__global__ __launch_bounds__(256)
void wdt_split_kernel(const float* __restrict__ Win, bf16_t* __restrict__ Whi,
                      bf16_t* __restrict__ Wlo) {
  const int h = threadIdx.x & 63;
  const int k0 = blockIdx.x * 256 + (threadIdx.x >> 6) * 64;
#pragma unroll 4
  for (int i = 0; i < 64; ++i) {
    int k = k0 + i;
    float v = Win[(size_t)k * 8512 + 8448 + h];
    bf16_t hv = (bf16_t)v;
    Whi[(size_t)h * DMODEL + k] = hv;
    Wlo[(size_t)h * DMODEL + k] = (bf16_t)(v - (float)hv);
  }
}

// ---------------- 256x256 GEMM, 1 barrier/K-tile + in-tile read-ahead ----------------
// 512 threads = 8 waves (2M x 4N), BK=64, 128KB LDS double-buffered.
// LDS in MFMA-fragment order. All staging for tile t+1 issued during tile t;
// single vmcnt(0)+barrier at tile top makes whole buf readable. Within a tile,
// ds_reads are issued one MFMA-cluster ahead so lgkmcnt(0) lands pre-hidden.
// Quadrant order C00,C01,C11,C10: B0 held in regs (no re-read).
// Column split: cols [0,splitN) -> C0 (ld=splitN), [splitN,N) -> C1.
template <typename OutT>
__global__ __launch_bounds__(512, 2)
void gemm256(const bf16_t* __restrict__ A, const bf16_t* __restrict__ B,
             OutT* __restrict__ C0, OutT* __restrict__ C1,
             long M, long N, long K, long splitN, int gridX) {
  __shared__ bf16_t sA[2][2][8192];   // [buf][half][(f*2+s)*512 + lane*8 + e]
  __shared__ bf16_t sB[2][2][8192];
  const int tid = threadIdx.x;
  const int lane = tid & 63;
  const int wid = tid >> 6;          // 0..7
  const int wr = wid >> 2;           // 0..1  (M)
  const int wc = wid & 3;            // 0..3  (N)

  // XCD chunk (contiguous, rows 4x..4x+3) iterated column-major for L2 reuse.
  // requires gridDim.x == 8 * 4 * gridX (holds for both call sites).
  const int x = blockIdx.x & 7;
  const int q = blockIdx.x >> 3;     // 0..cpx-1
  const long bm = (long)(x * 4 + (q & 3)) * 256;
  const long bn = (long)(q >> 2) * 256;

  // staging source mapping (fragment order): wave wid stages its slice
  const int srow = (wid >> 1) * 16 + (lane & 15);      // + c*64 within 128-row half
  const int skof = (wid & 1) * 32 + (lane >> 4) * 8;   // k within 64-k tile
  const bf16_t* Abase = A + (bm + srow) * K + skof;
  const bf16_t* Bbase = B + (bn + srow) * K + skof;

  auto stageA = [&](int buf, int h, long kt) {
    const bf16_t* s = Abase + (long)h * 128 * K + kt;
    gld16(s,          &sA[buf][h][wid * 512]);
    gld16(s + 64 * K, &sA[buf][h][4096 + wid * 512]);
  };
  auto stageB = [&](int buf, int h, long kt) {
    const bf16_t* s = Bbase + (long)h * 128 * K + kt;
    gld16(s,          &sB[buf][h][wid * 512]);
    gld16(s + 64 * K, &sB[buf][h][4096 + wid * 512]);
  };

  // LDS byte-address bases for opaque reads
  const unsigned sAb = (unsigned)(uintptr_t)(__attribute__((address_space(3))) void*)&sA[0][0][0]
                       + (unsigned)lane * 16 + (unsigned)wr * 8192;
  const unsigned sBb = (unsigned)(uintptr_t)(__attribute__((address_space(3))) void*)&sB[0][0][0]
                       + (unsigned)lane * 16 + (unsigned)wc * 4096;

  // prologue: stage tile 0 (8 loads)
  stageA(0, 0, 0); stageB(0, 0, 0); stageB(0, 1, 0); stageA(0, 1, 0);

  f32x4 acc[8][4] = {};
  bf16x8 a0[4][2], a1[4][2], b0[2][2], b1[2][2];
  int cur = 0;
  const int NT = (int)(K >> 6);

  for (int t = 0; t < NT; ++t) {
    const bool fin = (t == NT - 1);
    const long ktn = (long)(t + 1) * 64;
    const unsigned ab = sAb + (unsigned)cur * 32768;
    const unsigned bb = sBb + (unsigned)cur * 32768;

    // tile top: whole buf[cur] staged (8 loads issued last tile) -> drain + barrier
    asm volatile("s_waitcnt vmcnt(0)\n\ts_barrier" ::: "memory");

    // reads for C00 (A-h0: 8, B-h0: 4)
#pragma unroll
    for (int mi = 0; mi < 4; ++mi) {
      a0[mi][0] = ldsr(ab + (mi*2+0)*1024);
      a0[mi][1] = ldsr(ab + (mi*2+1)*1024);
    }
#pragma unroll
    for (int ni = 0; ni < 2; ++ni) {
      b0[ni][0] = ldsr(bb + (ni*2+0)*1024);
      b0[ni][1] = ldsr(bb + (ni*2+1)*1024);
    }
    if (!fin) { stageA(cur ^ 1, 0, ktn); stageB(cur ^ 1, 0, ktn); }
    asm volatile("s_waitcnt lgkmcnt(0)" ::: "memory");
    __builtin_amdgcn_sched_barrier(0);

    // read-ahead B-h1 (hidden under C00)
#pragma unroll
    for (int ni = 0; ni < 2; ++ni) {
      b1[ni][0] = ldsr(bb + 16384 + (ni*2+0)*1024);
      b1[ni][1] = ldsr(bb + 16384 + (ni*2+1)*1024);
    }
    if (!fin) stageB(cur ^ 1, 1, ktn);
    __builtin_amdgcn_sched_barrier(0);
    __builtin_amdgcn_s_setprio(1);
#pragma unroll
    for (int mi = 0; mi < 4; ++mi)
#pragma unroll
      for (int ni = 0; ni < 2; ++ni) {
        acc[mi][ni] = mfma16(a0[mi][0], b0[ni][0], acc[mi][ni]);
        acc[mi][ni] = mfma16(a0[mi][1], b0[ni][1], acc[mi][ni]);
      }
    __builtin_amdgcn_s_setprio(0);
    __builtin_amdgcn_sched_barrier(0);
    asm volatile("s_waitcnt lgkmcnt(0)" ::: "memory");   // b1 ready (covered by C00)
    __builtin_amdgcn_sched_barrier(0);

    // read-ahead A-h1 (hidden under C01)
#pragma unroll
    for (int mi = 0; mi < 4; ++mi) {
      a1[mi][0] = ldsr(ab + 16384 + (mi*2+0)*1024);
      a1[mi][1] = ldsr(ab + 16384 + (mi*2+1)*1024);
    }
    if (!fin) stageA(cur ^ 1, 1, ktn);
    __builtin_amdgcn_sched_barrier(0);
    __builtin_amdgcn_s_setprio(1);
#pragma unroll
    for (int mi = 0; mi < 4; ++mi)
#pragma unroll
      for (int ni = 0; ni < 2; ++ni) {
        acc[mi][2 + ni] = mfma16(a0[mi][0], b1[ni][0], acc[mi][2 + ni]);
        acc[mi][2 + ni] = mfma16(a0[mi][1], b1[ni][1], acc[mi][2 + ni]);
      }
    __builtin_amdgcn_s_setprio(0);
    __builtin_amdgcn_sched_barrier(0);
    asm volatile("s_waitcnt lgkmcnt(0)" ::: "memory");   // a1 ready (covered by C01)
    __builtin_amdgcn_sched_barrier(0);

    // C11 then C10 (no reads; staging drains under these 32 MFMAs)
    __builtin_amdgcn_s_setprio(1);
#pragma unroll
    for (int mi = 0; mi < 4; ++mi)
#pragma unroll
      for (int ni = 0; ni < 2; ++ni) {
        acc[4 + mi][2 + ni] = mfma16(a1[mi][0], b1[ni][0], acc[4 + mi][2 + ni]);
        acc[4 + mi][2 + ni] = mfma16(a1[mi][1], b1[ni][1], acc[4 + mi][2 + ni]);
      }
#pragma unroll
    for (int mi = 0; mi < 4; ++mi)
#pragma unroll
      for (int ni = 0; ni < 2; ++ni) {
        acc[4 + mi][ni] = mfma16(a1[mi][0], b0[ni][0], acc[4 + mi][ni]);
        acc[4 + mi][ni] = mfma16(a1[mi][1], b0[ni][1], acc[4 + mi][ni]);
      }
    __builtin_amdgcn_s_setprio(0);
    __builtin_amdgcn_sched_barrier(0);
    cur ^= 1;
  }

  // epilogue
  const int cr = (lane >> 4) * 4;
  const int cc = lane & 15;
  OutT* Cb;
  long col0, ldc;
  if (bn < splitN) { Cb = C0; col0 = bn; ldc = splitN; }
  else             { Cb = C1; col0 = bn - splitN; ldc = N - splitN; }
#pragma unroll
  for (int mi = 0; mi < 8; ++mi) {
    long row = bm + (mi >> 2) * 128 + wr * 64 + (mi & 3) * 16 + cr;
#pragma unroll
    for (int ni = 0; ni < 4; ++ni) {
      long col = col0 + (ni >> 1) * 128 + wc * 32 + (ni & 1) * 16 + cc;
      OutT* p = Cb + row * ldc + col;
#pragma unroll
      for (int r = 0; r < 4; ++r) p[(long)r * ldc] = (OutT)acc[mi][ni][r];
    }
  }
}

// ---------------- dt via split-bf16 MFMA: hi*hi + hi*lo + lo*hi ----------------
__global__ __launch_bounds__(256)
void dt_mfma_kernel(const bf16_t* __restrict__ Ahi, const bf16_t* __restrict__ Alo,
                    const bf16_t* __restrict__ Whi, const bf16_t* __restrict__ Wlo,
                    float* __restrict__ dtraw) {
  __shared__ bf16_t sAh[4096], sAl[4096], sBh[2048], sBl[2048];
  const int tid = threadIdx.x;
  const int lane = tid & 63;
  const int w = tid >> 6;
  const long bm = (long)blockIdx.x * 128;
  const int rlo = lane & 15;
  const int kq = lane >> 4;

  const bf16_t* Ah0 = Ahi + (bm + 2*w*16 + rlo) * (long)DMODEL + kq*8;
  const bf16_t* Ah1 = Ah0 + 16*(long)DMODEL;
  const bf16_t* Al0 = Alo + (bm + 2*w*16 + rlo) * (long)DMODEL + kq*8;
  const bf16_t* Al1 = Al0 + 16*(long)DMODEL;
  const bf16_t* Bh0 = Whi + (w*16 + rlo) * (long)DMODEL + kq*8;
  const bf16_t* Bl0 = Wlo + (w*16 + rlo) * (long)DMODEL + kq*8;

  f32x4 acc[2][4] = {};

  for (int kt = 0; kt < DMODEL; kt += 32) {
    __syncthreads();
    gld16(Ah0 + kt, &sAh[(2*w)*512]);
    gld16(Ah1 + kt, &sAh[(2*w+1)*512]);
    gld16(Al0 + kt, &sAl[(2*w)*512]);
    gld16(Al1 + kt, &sAl[(2*w+1)*512]);
    gld16(Bh0 + kt, &sBh[w*512]);
    gld16(Bl0 + kt, &sBl[w*512]);
    __syncthreads();
    bf16x8 ah[2], al[2], bh[4], bl[4];
#pragma unroll
    for (int i = 0; i < 2; ++i) {
      ah[i] = *(const bf16x8*)&sAh[((2*w + i)*64 + lane)*8];
      al[i] = *(const bf16x8*)&sAl[((2*w + i)*64 + lane)*8];
    }
#pragma unroll
    for (int n = 0; n < 4; ++n) {
      bh[n] = *(const bf16x8*)&sBh[(n*64 + lane)*8];
      bl[n] = *(const bf16x8*)&sBl[(n*64 + lane)*8];
    }
#pragma unroll
    for (int mi = 0; mi < 2; ++mi)
#pragma unroll
      for (int n = 0; n < 4; ++n) {
        acc[mi][n] = mfma16(ah[mi], bh[n], acc[mi][n]);
        acc[mi][n] = mfma16(ah[mi], bl[n], acc[mi][n]);
        acc[mi][n] = mfma16(al[mi], bh[n], acc[mi][n]);
      }
  }

  const int cr = (lane >> 4) * 4;
  const int cc = lane & 15;
#pragma unroll
  for (int mi = 0; mi < 2; ++mi)
#pragma unroll
    for (int n = 0; n < 4; ++n)
#pragma unroll
      for (int r = 0; r < 4; ++r)
        dtraw[(bm + 2*w*16 + mi*16 + cr + r) * 64 + n*16 + cc] = acc[mi][n][r];
}

// ---------------- causal conv1d (K=4) + SiLU, split x/B/C ----------------
__global__ __launch_bounds__(256)
void conv_kernel(const bf16_t* __restrict__ xbc, const float* __restrict__ cw,
                 const float* __restrict__ cb, bf16_t* __restrict__ xo,
                 bf16_t* __restrict__ Bout, bf16_t* __restrict__ Cout) {
  const int c = blockIdx.x * 256 + threadIdx.x;
  const int t0 = blockIdx.y * 8;
  const int bstart = (t0 >> 12) << 12;
  const float w0 = cw[c*4+0], w1 = cw[c*4+1], w2 = cw[c*4+2], w3 = cw[c*4+3];
  const float bias = cb[c];
  float in[11];
#pragma unroll
  for (int k = 0; k < 11; ++k) {
    int t = t0 - 3 + k;
    in[k] = (t >= bstart) ? (float)xbc[(size_t)t * XBCN + c] : 0.f;
  }
#pragma unroll
  for (int i = 0; i < 8; ++i) {
    float v = bias + w0*in[i] + w1*in[i+1] + w2*in[i+2] + w3*in[i+3];
    float s = v / (1.f + __expf(-v));
    int t = t0 + i;
    bf16_t o = (bf16_t)s;
    if (c < DINNER)           xo[(size_t)t * DINNER + c] = o;
    else if (c < DINNER+128)  Bout[(size_t)t * DSTATE + (c - DINNER)] = o;
    else                      Cout[(size_t)t * DSTATE + (c - DINNER - 128)] = o;
  }
}

// ---------------- softplus(dt)+cumsum(dA) per (b,chunk,head) ----------------
__global__ __launch_bounds__(256)
void dt_scan_kernel(const float* __restrict__ dtraw, const float* __restrict__ dt_bias,
                    const float* __restrict__ Avec, float* __restrict__ dt_s,
                    float* __restrict__ dAcs, float* __restrict__ cdec) {
  const int wid = blockIdx.x * 4 + (threadIdx.x >> 6);
  const int lane = threadIdx.x & 63;
  const int h = wid & 63;
  const int bc = wid >> 6;
  const long tok0 = (long)bc * 128;
  const float Ah = Avec[h];
  const float bias = dt_bias[h];
  float v0 = dtraw[(tok0 + lane)*64 + h] + bias;
  float v1 = dtraw[(tok0 + 64 + lane)*64 + h] + bias;
  float d0 = (v0 > 20.f) ? v0 : log1pf(expf(v0));
  float d1 = (v1 > 20.f) ? v1 : log1pf(expf(v1));
  float s0 = d0 * Ah;
  float s1 = d1 * Ah;
#pragma unroll
  for (int off = 1; off < 64; off <<= 1) {
    float t = __shfl_up(s0, off);
    if (lane >= off) s0 += t;
  }
  float tot0 = __shfl(s0, 63);
#pragma unroll
  for (int off = 1; off < 64; off <<= 1) {
    float t = __shfl_up(s1, off);
    if (lane >= off) s1 += t;
  }
  s1 += tot0;
  const size_t base = (size_t)wid * 128;
  dt_s[base + lane] = d0;
  dt_s[base + 64 + lane] = d1;
  dAcs[base + lane] = s0;
  dAcs[base + 64 + lane] = s1;
  if (lane == 63) cdec[wid] = __expf(s1);
}

// ---------------- per-chunk states: dtx^T @ (decay .* Bm) -> (64 x 128) bf16 ----------------
__global__ __launch_bounds__(256)
void states_kernel(const bf16_t* __restrict__ x, const bf16_t* __restrict__ Bm,
                   const float* __restrict__ dt_s, const float* __restrict__ dAcs,
                   bf16_t* __restrict__ states) {
  __shared__ bf16_t sDtx[8192];
  __shared__ bf16_t sBd[16384];
  __shared__ float sDt[128];
  __shared__ float sDec[128];
  const int wid = blockIdx.x;
  const int h = wid & 63;
  const int bc = wid >> 6;
  const int tid = threadIdx.x;
  const int lane = tid & 63;
  const int w = tid >> 6;
  const long tok0 = (long)bc * 128;
  const size_t dbase = (size_t)wid * 128;

  if (tid < 128) {
    sDt[tid] = dt_s[dbase + tid];
  } else {
    int j = tid - 128;
    sDec[j] = __expf(dAcs[dbase + 127] - dAcs[dbase + j]);
  }
  __syncthreads();

  {
    const int jj0 = tid >> 3;
    const int pg = (tid & 7) * 8;
#pragma unroll
    for (int t = 0; t < 4; ++t) {
      int j = t*32 + jj0;
      bf16x8 xv = *(const bf16x8*)&x[(tok0 + j)*(long)DINNER + h*64 + pg];
      float dtj = sDt[j];
      int kq = (j >> 5) * 4;
      int qe = ((j >> 3) & 3) * 16;
      int e = j & 7;
#pragma unroll
      for (int i = 0; i < 8; ++i) {
        int p = pg + i;
        sDtx[((kq + (p>>4))*64 + qe + (p&15))*8 + e] = (bf16_t)((float)xv[i]*dtj);
      }
    }
    const int jj1 = tid >> 4;
    const int ng = (tid & 15) * 8;
#pragma unroll
    for (int t = 0; t < 8; ++t) {
      int j = t*16 + jj1;
      bf16x8 bv = *(const bf16x8*)&Bm[(tok0 + j)*(long)DSTATE + ng];
      float dec = sDec[j];
      int kq = (j >> 5) * 8;
      int qe = ((j >> 3) & 3) * 16;
      int e = j & 7;
#pragma unroll
      for (int i = 0; i < 8; ++i) {
        int n = ng + i;
        sBd[((kq + (n>>4))*64 + qe + (n&15))*8 + e] = (bf16_t)((float)bv[i]*dec);
      }
    }
  }
  __syncthreads();

  f32x4 acc[4][2] = {};
#pragma unroll
  for (int kt = 0; kt < 4; ++kt) {
    bf16x8 aF[4], bF[2];
#pragma unroll
    for (int mt = 0; mt < 4; ++mt) aF[mt] = *(const bf16x8*)&sDtx[((kt*4 + mt)*64 + lane)*8];
#pragma unroll
    for (int nt = 0; nt < 2; ++nt) bF[nt] = *(const bf16x8*)&sBd[((kt*8 + w*2 + nt)*64 + lane)*8];
#pragma unroll
    for (int mt = 0; mt < 4; ++mt)
#pragma unroll
      for (int nt = 0; nt < 2; ++nt)
        acc[mt][nt] = mfma16(aF[mt], bF[nt], acc[mt][nt]);
  }

  bf16_t* S = states + (size_t)wid * (HD * DSTATE);
  const int cr = (lane >> 4) * 4;
  const int cc = lane & 15;
#pragma unroll
  for (int mt = 0; mt < 4; ++mt)
#pragma unroll
    for (int nt = 0; nt < 2; ++nt) {
      int n = (w*2 + nt)*16 + cc;
#pragma unroll
      for (int r = 0; r < 4; ++r) {
        int p = mt*16 + cr + r;
        S[(size_t)p*DSTATE + n] = (bf16_t)acc[mt][nt][r];
      }
    }
}

// ---------------- inter-chunk scan over 32 chunks (in-place: states -> prevs) ----------------
__global__ __launch_bounds__(256)
void scan_kernel(bf16_t* __restrict__ sp, const float* __restrict__ cdec) {
  const size_t gid = (size_t)blockIdx.x * 256 + threadIdx.x;
  const int n = gid & 127;
  const int p = (gid >> 7) & 63;
  const int h = (gid >> 13) & 63;
  const int b = (int)(gid >> 19);
  float prev = 0.f;
  const size_t pn = (size_t)p * 128 + n;
  for (int c = 0; c < 32; ++c) {
    const int wid = (b*32 + c)*64 + h;
    const size_t idx = (size_t)wid * 8192 + pn;
    float s = (float)sp[idx];
    sp[idx] = (bf16_t)prev;
    prev = cdec[wid] * prev + s;
  }
}

// ---------------- per-chunk Y: inter + intra + D*x (in-place over x) ----------------
__global__ __launch_bounds__(256)
void ssd_y_kernel(bf16_t* __restrict__ xy, const bf16_t* __restrict__ Bm,
                  const bf16_t* __restrict__ Cm, const bf16_t* __restrict__ prevs,
                  const float* __restrict__ dt_s, const float* __restrict__ dAcs,
                  const float* __restrict__ Dvec) {
  __shared__ bf16_t sG[16384];
  __shared__ bf16_t sDtx[8192];
  __shared__ float sDA[128];
  __shared__ float sEA[128];
  __shared__ float sDt[128];

  const int wid = blockIdx.x;
  const int h = wid & 63;
  const int bc = wid >> 6;
  const int tid = threadIdx.x;
  const int lane = tid & 63;
  const int w = tid >> 6;
  const long tok0 = (long)bc * 128;
  const size_t dbase = (size_t)wid * 128;

  if (tid < 128) {
    float v = dAcs[dbase + tid];
    sDA[tid] = v;
    sEA[tid] = __expf(v);
  } else {
    sDt[tid - 128] = dt_s[dbase + tid - 128];
  }
  __syncthreads();

  {
    const int jj0 = tid >> 3;
    const int pg = (tid & 7) * 8;
#pragma unroll
    for (int t = 0; t < 4; ++t) {
      int j = t*32 + jj0;
      bf16x8 xv = *(const bf16x8*)&xy[(tok0 + j)*(long)DINNER + h*64 + pg];
      float dtj = sDt[j];
      int kq = (j >> 5) * 4;
      int qe = ((j >> 3) & 3) * 16;
      int e = j & 7;
#pragma unroll
      for (int i = 0; i < 8; ++i) {
        int p = pg + i;
        sDtx[((kq + (p>>4))*64 + qe + (p&15))*8 + e] = (bf16_t)((float)xv[i]*dtj);
      }
    }
  }

  const int arow = (w*2)*16 + (lane & 15);
  const int koff = (lane >> 4) * 8;
  bf16x8 aCm[2][4];
#pragma unroll
  for (int mi = 0; mi < 2; ++mi)
#pragma unroll
    for (int kt = 0; kt < 4; ++kt)
      aCm[mi][kt] = *(const bf16x8*)&Cm[(tok0 + arow + mi*16)*(long)DSTATE + kt*32 + koff];

  const bf16_t* P = prevs + (size_t)wid * 8192;
  f32x4 accY[2][4] = {};
#pragma unroll
  for (int kt = 0; kt < 4; ++kt) {
    bf16x8 bP[4];
#pragma unroll
    for (int ni = 0; ni < 4; ++ni)
      bP[ni] = *(const bf16x8*)&P[(size_t)(ni*16 + (lane & 15))*DSTATE + kt*32 + koff];
#pragma unroll
    for (int mi = 0; mi < 2; ++mi)
#pragma unroll
      for (int ni = 0; ni < 4; ++ni)
        accY[mi][ni] = mfma16(aCm[mi][kt], bP[ni], accY[mi][ni]);
  }
  const int cr = (lane >> 4) * 4;
  const int cc = lane & 15;
#pragma unroll
  for (int mi = 0; mi < 2; ++mi)
#pragma unroll
    for (int r = 0; r < 4; ++r) {
      float e = sEA[(w*2 + mi)*16 + cr + r];
#pragma unroll
      for (int ni = 0; ni < 4; ++ni) accY[mi][ni][r] *= e;
    }

  f32x4 accS[2][8] = {};
#pragma unroll
  for (int kt = 0; kt < 4; ++kt) {
    bf16x8 bB[8];
#pragma unroll
    for (int nt = 0; nt < 8; ++nt)
      bB[nt] = *(const bf16x8*)&Bm[(tok0 + nt*16 + (lane & 15))*(long)DSTATE + kt*32 + koff];
#pragma unroll
    for (int mi = 0; mi < 2; ++mi)
#pragma unroll
      for (int nt = 0; nt < 8; ++nt)
        accS[mi][nt] = mfma16(aCm[mi][kt], bB[nt], accS[mi][nt]);
  }

#pragma unroll
  for (int mi = 0; mi < 2; ++mi)
#pragma unroll
    for (int nt = 0; nt < 8; ++nt)
#pragma unroll
      for (int r = 0; r < 4; ++r) {
        int i = (w*2 + mi)*16 + cr + r;
        int j = nt*16 + cc;
        float g = (i >= j) ? accS[mi][nt][r] * __expf(sDA[i] - sDA[j]) : 0.f;
        sG[(((j>>5)*8 + (i>>4))*64 + ((j>>3)&3)*16 + (i&15))*8 + (j&7)] = (bf16_t)g;
      }
  __syncthreads();

#pragma unroll
  for (int kt = 0; kt < 4; ++kt) {
    bf16x8 aG[2], bD[4];
#pragma unroll
    for (int mi = 0; mi < 2; ++mi) aG[mi] = *(const bf16x8*)&sG[((kt*8 + w*2 + mi)*64 + lane)*8];
#pragma unroll
    for (int ni = 0; ni < 4; ++ni) bD[ni] = *(const bf16x8*)&sDtx[((kt*4 + ni)*64 + lane)*8];
#pragma unroll
    for (int mi = 0; mi < 2; ++mi)
#pragma unroll
      for (int ni = 0; ni < 4; ++ni)
        accY[mi][ni] = mfma16(aG[mi], bD[ni], accY[mi][ni]);
  }

  const float Dh = Dvec[h];
#pragma unroll
  for (int mi = 0; mi < 2; ++mi)
#pragma unroll
    for (int ni = 0; ni < 4; ++ni)
#pragma unroll
      for (int r = 0; r < 4; ++r) {
        long tokr = tok0 + (w*2 + mi)*16 + cr + r;
        int p = ni*16 + cc;
        long idx = tokr * DINNER + h*64 + p;
        float xv = (float)xy[idx];
        xy[idx] = (bf16_t)(accY[mi][ni][r] + Dh * xv);
      }
}

// ---------------- gating + RMS norm ----------------
__global__ __launch_bounds__(256)
void gate_kernel(const bf16_t* __restrict__ y, const bf16_t* __restrict__ z,
                 const float* __restrict__ norm_w, bf16_t* __restrict__ yn) {
  const int tok = blockIdx.x;
  const int tid = threadIdx.x;
  const int lane = tid & 63;
  const int w = tid >> 6;
  const bf16_t* yrow = y + (size_t)tok * DINNER;
  const bf16_t* zrow = z + (size_t)tok * DINNER;
  float local[16];
  float ss = 0.f;
#pragma unroll
  for (int v = 0; v < 2; ++v) {
    int col = tid*16 + v*8;
    bf16x8 yv = *(const bf16x8*)&yrow[col];
    bf16x8 zv = *(const bf16x8*)&zrow[col];
#pragma unroll
    for (int i = 0; i < 8; ++i) {
      float zf = (float)zv[i];
      float g = zf / (1.f + __expf(-zf));
      float t = (float)yv[i] * g;
      local[v*8 + i] = t;
      ss += t*t;
    }
  }
#pragma unroll
  for (int off = 32; off > 0; off >>= 1) ss += __shfl_xor(ss, off);
  __shared__ float red[4];
  if (lane == 0) red[w] = ss;
  __syncthreads();
  float rms = rsqrtf((red[0]+red[1]+red[2]+red[3]) * (1.f/DINNER) + 1e-5f);
  bf16_t* orow = yn + (size_t)tok * DINNER;
#pragma unroll
  for (int v = 0; v < 2; ++v) {
    int col = tid*16 + v*8;
    bf16x8 o;
#pragma unroll
    for (int i = 0; i < 8; ++i) o[i] = (bf16_t)(local[v*8+i] * rms * norm_w[col+i]);
    *(bf16x8*)&orow[col] = o;
  }
}

// ---------------- launch ----------------
extern "C" void kernel_launch(void* const* d_in, const int* in_sizes, int n_in,
                              void* d_out, int out_size, void* d_ws, size_t ws_size,
                              hipStream_t stream) {
  const float* hidden  = (const float*)d_in[0];
  const float* W_in    = (const float*)d_in[1];
  const float* conv_w  = (const float*)d_in[2];
  const float* conv_b  = (const float*)d_in[3];
  const float* Avec    = (const float*)d_in[4];
  const float* Dvec    = (const float*)d_in[5];
  const float* dt_bias = (const float*)d_in[6];
  const float* norm_w  = (const float*)d_in[7];
  const float* W_out   = (const float*)d_in[8];

  char* ws = (char*)d_ws;
  size_t off = 0;
  auto take = [&](size_t bytes) -> char* {
    char* p = ws + off;
    off += (bytes + 255) & ~(size_t)255;
    return p;
  };
  bf16_t* R1    = (bf16_t*)take((size_t)NBC * NH * HD * DSTATE * 2);  // Xb -> states -> ynbuf
  bf16_t* WinT  = (bf16_t*)take((size_t)WINT_ROWS * DMODEL * 2);      // later WoutT
  bf16_t* xbc   = (bf16_t*)take((size_t)TOK * XBCN * 2);              // Xlo lives here first
  bf16_t* xconv = (bf16_t*)take((size_t)TOK * DINNER * 2);            // y in-place
  bf16_t* Bmat  = (bf16_t*)take((size_t)TOK * DSTATE * 2);
  bf16_t* Cmat  = (bf16_t*)take((size_t)TOK * DSTATE * 2);
  float*  dtraw = (float*)take((size_t)TOK * NH * 4);
  float*  dt_s  = (float*)take((size_t)TOK * NH * 4);
  float*  dAcs  = (float*)take((size_t)TOK * NH * 4);
  float*  cdec  = (float*)take((size_t)NBC * NH * 4);
  bf16_t* Wdth  = (bf16_t*)take((size_t)NH * DMODEL * 2);
  bf16_t* Wdtl  = (bf16_t*)take((size_t)NH * DMODEL * 2);
  if (off > ws_size) return;

  bf16_t* Xb      = R1;
  bf16_t* Xlo     = xbc;               // dead before xbc-gemm writes
  bf16_t* statesB = R1;
  bf16_t* ynbuf   = R1;
  bf16_t* WoutT   = WinT;
  bf16_t* zbuf    = (bf16_t*)d_out;    // z as bf16 in d_out
  float*  out     = (float*)d_out;

  cast_split_kernel<<<(TOK*DMODEL)/2048, 256, 0, stream>>>(hidden, Xb, Xlo, (size_t)TOK*DMODEL);
  wdt_split_kernel<<<DMODEL/256, 256, 0, stream>>>(W_in, Wdth, Wdtl);
  dt_mfma_kernel<<<TOK/128, 256, 0, stream>>>(Xb, Xlo, Wdth, Wdtl, dtraw);
  transpose_cast_kernel<<<dim3(WINT_ROWS/32, DMODEL/32), 256, 0, stream>>>(W_in, WinT, DMODEL, 8512, WINT_ROWS);
  // fused in-proj: cols [0,4096) -> zbuf, [4096,8448) -> xbc
  gemm256<bf16_t><<<(TOK/256)*(WINT_ROWS/256), 512, 0, stream>>>(
      Xb, WinT, zbuf, xbc, TOK, WINT_ROWS, DMODEL, DINNER, WINT_ROWS/256);
  transpose_cast_kernel<<<dim3(DMODEL/32, DINNER/32), 256, 0, stream>>>(W_out, WoutT, DINNER, DMODEL, DMODEL);
  conv_kernel<<<dim3(XBCN/256, TOK/8), 256, 0, stream>>>(xbc, conv_w, conv_b, xconv, Bmat, Cmat);
  dt_scan_kernel<<<(NBC*NH)/4, 256, 0, stream>>>(dtraw, dt_bias, Avec, dt_s, dAcs, cdec);
  states_kernel<<<NBC*NH, 256, 0, stream>>>(xconv, Bmat, dt_s, dAcs, statesB);
  scan_kernel<<<(NBC*NH*HD*DSTATE)/(32*256), 256, 0, stream>>>(statesB, cdec);
  ssd_y_kernel<<<NBC*NH, 256, 0, stream>>>(xconv, Bmat, Cmat, statesB, dt_s, dAcs, Dvec);
  gate_kernel<<<TOK, 256, 0, stream>>>(xconv, zbuf, norm_w, ynbuf);
  // out-proj
  gemm256<float><<<(TOK/256)*(DMODEL/256), 512, 0, stream>>>(
      ynbuf, WoutT, out, out, TOK, DMODEL, DINNER, DMODEL, DMODEL/256);
}

// Round 8
// 1040.503 us; speedup vs baseline: 1.0120x; 1.0120x over previous
//
#include <hip/hip_runtime.h>
#include <hip/hip_bf16.h>

typedef __bf16 bf16_t;
typedef bf16_t bf16x8 __attribute__((ext_vector_type(8)));
typedef float f32x4 __attribute__((ext_vector_type(4)));

#define TOK 8192          // B*S
#define DMODEL 2048
#define DINNER 4096
#define XBCN 4352         // conv dim = 34*128
#define DSTATE 128
#define NH 64
#define HD 64
#define NBC 64            // B * (S/CHUNK) = 2*32
#define WINT_ROWS 8448    // z (4096) + xbc (4352)

// async global->LDS, 16B per lane, LDS dest = wave-uniform base + lane*16
__device__ __forceinline__ void gld16(const bf16_t* g, bf16_t* l) {
  __builtin_amdgcn_global_load_lds((const __attribute__((address_space(1))) void*)g,
                                   (__attribute__((address_space(3))) void*)l, 16, 0, 0);
}

__device__ __forceinline__ f32x4 mfma16(bf16x8 a, bf16x8 b, f32x4 c) {
  return __builtin_amdgcn_mfma_f32_16x16x32_bf16(a, b, c, 0, 0, 0);
}

// opaque LDS read: compiler cannot link it to global_load_lds's LDS writes,
// so it emits NO vmcnt waits for it; we do our own counted vmcnt + lgkmcnt.
__device__ __forceinline__ bf16x8 ldsr(unsigned addr) {
  f32x4 r;
  asm volatile("ds_read_b128 %0, %1" : "=v"(r) : "v"(addr));
  return __builtin_bit_cast(bf16x8, r);
}

// ---------------- utility kernels ----------------

// hidden f32 -> hi (bf16) + lo (bf16 residual)
__global__ __launch_bounds__(256)
void cast_split_kernel(const float* __restrict__ in, bf16_t* __restrict__ hi,
                       bf16_t* __restrict__ lo, size_t n) {
  size_t i = ((size_t)blockIdx.x * 256 + threadIdx.x) * 8;
  if (i + 8 > n) return;
  float4 a = *(const float4*)(in + i);
  float4 b = *(const float4*)(in + i + 4);
  float v[8] = {a.x,a.y,a.z,a.w,b.x,b.y,b.z,b.w};
  bf16x8 h, l;
#pragma unroll
  for (int j = 0; j < 8; ++j) {
    h[j] = (bf16_t)v[j];
    l[j] = (bf16_t)(v[j] - (float)h[j]);
  }
  *(bf16x8*)(hi + i) = h;
  *(bf16x8*)(lo + i) = l;
}

// in: R x C f32 row-major -> out: outRows x R bf16 (out[c][r] = in[r][c])
__global__ __launch_bounds__(256)
void transpose_cast_kernel(const float* __restrict__ in, bf16_t* __restrict__ out,
                           int R, int C, int outRows) {
  __shared__ float tile[32][33];
  const int c0 = blockIdx.x * 32;
  const int r0 = blockIdx.y * 32;
  const int tx = threadIdx.x & 31;
  const int ty = threadIdx.x >> 5;
#pragma unroll
  for (int k = 0; k < 4; ++k) {
    int r = r0 + ty + k*8;
    int c = c0 + tx;
    tile[ty + k*8][tx] = (c < C) ? in[(size_t)r * C + c] : 0.f;
  }
  __syncthreads();
#pragma unroll
  for (int k = 0; k < 4; ++k) {
    int oc = c0 + ty + k*8;
    int orr = r0 + tx;
    out[(size_t)oc * R + orr] = (bf16_t)tile[tx][ty + k*8];
  }
}

// W_in dt columns -> Whi/Wlo [64][2048] bf16 split
__global__ __launch_bounds__(256)
void wdt_split_kernel(const float* __restrict__ Win, bf16_t* __restrict__ Whi,
                      bf16_t* __restrict__ Wlo) {
  const int h = threadIdx.x & 63;
  const int k0 = blockIdx.x * 256 + (threadIdx.x >> 6) * 64;
#pragma unroll 4
  for (int i = 0; i < 64; ++i) {
    int k = k0 + i;
    float v = Win[(size_t)k * 8512 + 8448 + h];
    bf16_t hv = (bf16_t)v;
    Whi[(size_t)h * DMODEL + k] = hv;
    Wlo[(size_t)h * DMODEL + k] = (bf16_t)(v - (float)hv);
  }
}

// ---------------- 256x256 GEMM: 1 barrier/K-tile, full-tile staging cover ----------------
// 512 threads = 8 waves (2M x 4N), BK=64, 128KB LDS double-buffered, fragment-order
// LDS (conflict-free, no swizzle needed). Per tile: vmcnt(0)+barrier (staged loads had
// a FULL tile of cover), stage all 8 next-tile loads immediately (max cover), issue all
// 24 ds_reads, consume with counted lgkmcnt(12/8/0) each pre-covered by MFMA clusters.
// Each wave drains lgkm before next barrier -> staging can't race reads.
// Column split: cols [0,splitN) -> C0 (ld=splitN), [splitN,N) -> C1.
template <typename OutT>
__global__ __launch_bounds__(512, 2)
void gemm256(const bf16_t* __restrict__ A, const bf16_t* __restrict__ B,
             OutT* __restrict__ C0, OutT* __restrict__ C1,
             long M, long N, long K, long splitN, int gridX) {
  __shared__ bf16_t sA[2][2][8192];   // [buf][half][(f*2+s)*512 + lane*8 + e]
  __shared__ bf16_t sB[2][2][8192];
  const int tid = threadIdx.x;
  const int lane = tid & 63;
  const int wid = tid >> 6;          // 0..7
  const int wr = wid >> 2;           // 0..1  (M)
  const int wc = wid & 3;            // 0..3  (N)

  // XCD chunk (contiguous, rows 4x..4x+3) iterated column-major for L2 reuse.
  const int x = blockIdx.x & 7;
  const int q = blockIdx.x >> 3;
  const long bm = (long)(x * 4 + (q & 3)) * 256;
  const long bn = (long)(q >> 2) * 256;

  // staging source mapping (fragment order): wave wid stages its slice
  const int srow = (wid >> 1) * 16 + (lane & 15);
  const int skof = (wid & 1) * 32 + (lane >> 4) * 8;
  const bf16_t* Abase = A + (bm + srow) * K + skof;
  const bf16_t* Bbase = B + (bn + srow) * K + skof;

  auto stageA = [&](int buf, int h, long kt) {
    const bf16_t* s = Abase + (long)h * 128 * K + kt;
    gld16(s,          &sA[buf][h][wid * 512]);
    gld16(s + 64 * K, &sA[buf][h][4096 + wid * 512]);
  };
  auto stageB = [&](int buf, int h, long kt) {
    const bf16_t* s = Bbase + (long)h * 128 * K + kt;
    gld16(s,          &sB[buf][h][wid * 512]);
    gld16(s + 64 * K, &sB[buf][h][4096 + wid * 512]);
  };

  const unsigned sAb = (unsigned)(uintptr_t)(__attribute__((address_space(3))) void*)&sA[0][0][0]
                       + (unsigned)lane * 16 + (unsigned)wr * 8192;
  const unsigned sBb = (unsigned)(uintptr_t)(__attribute__((address_space(3))) void*)&sB[0][0][0]
                       + (unsigned)lane * 16 + (unsigned)wc * 4096;

  // prologue: stage tile 0 (8 loads)
  stageA(0, 0, 0); stageB(0, 0, 0); stageB(0, 1, 0); stageA(0, 1, 0);

  f32x4 acc[8][4] = {};
  bf16x8 a0[4][2], a1[4][2], b0[2][2], b1[2][2];
  int cur = 0;
  const int NT = (int)(K >> 6);

  for (int t = 0; t < NT; ++t) {
    const bool fin = (t == NT - 1);
    const long ktn = (long)(t + 1) * 64;
    const unsigned ab = sAb + (unsigned)cur * 32768;
    const unsigned bb = sBb + (unsigned)cur * 32768;

    // tile top: buf[cur] fully staged (loads had a whole tile of cover)
    asm volatile("s_waitcnt vmcnt(0)\n\ts_barrier" ::: "memory");

    // stage ALL next-tile loads NOW -> full-tile cover before next vmcnt(0)
    if (!fin) {
      stageA(cur ^ 1, 0, ktn);
      stageB(cur ^ 1, 0, ktn);
      stageB(cur ^ 1, 1, ktn);
      stageA(cur ^ 1, 1, ktn);
    }
    __builtin_amdgcn_sched_barrier(0);

    // issue all 24 ds_reads in wait order: a0(8), b0(4), b1(4), a1(8)
#pragma unroll
    for (int mi = 0; mi < 4; ++mi) {
      a0[mi][0] = ldsr(ab + (mi*2+0)*1024);
      a0[mi][1] = ldsr(ab + (mi*2+1)*1024);
    }
#pragma unroll
    for (int ni = 0; ni < 2; ++ni) {
      b0[ni][0] = ldsr(bb + (ni*2+0)*1024);
      b0[ni][1] = ldsr(bb + (ni*2+1)*1024);
    }
#pragma unroll
    for (int ni = 0; ni < 2; ++ni) {
      b1[ni][0] = ldsr(bb + 16384 + (ni*2+0)*1024);
      b1[ni][1] = ldsr(bb + 16384 + (ni*2+1)*1024);
    }
#pragma unroll
    for (int mi = 0; mi < 4; ++mi) {
      a1[mi][0] = ldsr(ab + 16384 + (mi*2+0)*1024);
      a1[mi][1] = ldsr(ab + 16384 + (mi*2+1)*1024);
    }
    __builtin_amdgcn_sched_barrier(0);

    // Q00: needs a0,b0 (oldest 12)
    asm volatile("s_waitcnt lgkmcnt(12)" ::: "memory");
    __builtin_amdgcn_sched_barrier(0);
    __builtin_amdgcn_s_setprio(1);
#pragma unroll
    for (int mi = 0; mi < 4; ++mi)
#pragma unroll
      for (int ni = 0; ni < 2; ++ni) {
        acc[mi][ni] = mfma16(a0[mi][0], b0[ni][0], acc[mi][ni]);
        acc[mi][ni] = mfma16(a0[mi][1], b0[ni][1], acc[mi][ni]);
      }
    __builtin_amdgcn_s_setprio(0);
    __builtin_amdgcn_sched_barrier(0);

    // Q01: needs b1 (covered by Q00)
    asm volatile("s_waitcnt lgkmcnt(8)" ::: "memory");
    __builtin_amdgcn_sched_barrier(0);
    __builtin_amdgcn_s_setprio(1);
#pragma unroll
    for (int mi = 0; mi < 4; ++mi)
#pragma unroll
      for (int ni = 0; ni < 2; ++ni) {
        acc[mi][2 + ni] = mfma16(a0[mi][0], b1[ni][0], acc[mi][2 + ni]);
        acc[mi][2 + ni] = mfma16(a0[mi][1], b1[ni][1], acc[mi][2 + ni]);
      }
    __builtin_amdgcn_s_setprio(0);
    __builtin_amdgcn_sched_barrier(0);

    // Q11 + Q10: needs a1 (covered by Q00+Q01); all reads drained before next barrier
    asm volatile("s_waitcnt lgkmcnt(0)" ::: "memory");
    __builtin_amdgcn_sched_barrier(0);
    __builtin_amdgcn_s_setprio(1);
#pragma unroll
    for (int mi = 0; mi < 4; ++mi)
#pragma unroll
      for (int ni = 0; ni < 2; ++ni) {
        acc[4 + mi][2 + ni] = mfma16(a1[mi][0], b1[ni][0], acc[4 + mi][2 + ni]);
        acc[4 + mi][2 + ni] = mfma16(a1[mi][1], b1[ni][1], acc[4 + mi][2 + ni]);
      }
#pragma unroll
    for (int mi = 0; mi < 4; ++mi)
#pragma unroll
      for (int ni = 0; ni < 2; ++ni) {
        acc[4 + mi][ni] = mfma16(a1[mi][0], b0[ni][0], acc[4 + mi][ni]);
        acc[4 + mi][ni] = mfma16(a1[mi][1], b0[ni][1], acc[4 + mi][ni]);
      }
    __builtin_amdgcn_s_setprio(0);
    __builtin_amdgcn_sched_barrier(0);
    cur ^= 1;
  }

  // epilogue
  const int cr = (lane >> 4) * 4;
  const int cc = lane & 15;
  OutT* Cb;
  long col0, ldc;
  if (bn < splitN) { Cb = C0; col0 = bn; ldc = splitN; }
  else             { Cb = C1; col0 = bn - splitN; ldc = N - splitN; }
#pragma unroll
  for (int mi = 0; mi < 8; ++mi) {
    long row = bm + (mi >> 2) * 128 + wr * 64 + (mi & 3) * 16 + cr;
#pragma unroll
    for (int ni = 0; ni < 4; ++ni) {
      long col = col0 + (ni >> 1) * 128 + wc * 32 + (ni & 1) * 16 + cc;
      OutT* p = Cb + row * ldc + col;
#pragma unroll
      for (int r = 0; r < 4; ++r) p[(long)r * ldc] = (OutT)acc[mi][ni][r];
    }
  }
}

// ---------------- dt via split-bf16 MFMA: hi*hi + hi*lo + lo*hi ----------------
__global__ __launch_bounds__(256)
void dt_mfma_kernel(const bf16_t* __restrict__ Ahi, const bf16_t* __restrict__ Alo,
                    const bf16_t* __restrict__ Whi, const bf16_t* __restrict__ Wlo,
                    float* __restrict__ dtraw) {
  __shared__ bf16_t sAh[4096], sAl[4096], sBh[2048], sBl[2048];
  const int tid = threadIdx.x;
  const int lane = tid & 63;
  const int w = tid >> 6;
  const long bm = (long)blockIdx.x * 128;
  const int rlo = lane & 15;
  const int kq = lane >> 4;

  const bf16_t* Ah0 = Ahi + (bm + 2*w*16 + rlo) * (long)DMODEL + kq*8;
  const bf16_t* Ah1 = Ah0 + 16*(long)DMODEL;
  const bf16_t* Al0 = Alo + (bm + 2*w*16 + rlo) * (long)DMODEL + kq*8;
  const bf16_t* Al1 = Al0 + 16*(long)DMODEL;
  const bf16_t* Bh0 = Whi + (w*16 + rlo) * (long)DMODEL + kq*8;
  const bf16_t* Bl0 = Wlo + (w*16 + rlo) * (long)DMODEL + kq*8;

  f32x4 acc[2][4] = {};

  for (int kt = 0; kt < DMODEL; kt += 32) {
    __syncthreads();
    gld16(Ah0 + kt, &sAh[(2*w)*512]);
    gld16(Ah1 + kt, &sAh[(2*w+1)*512]);
    gld16(Al0 + kt, &sAl[(2*w)*512]);
    gld16(Al1 + kt, &sAl[(2*w+1)*512]);
    gld16(Bh0 + kt, &sBh[w*512]);
    gld16(Bl0 + kt, &sBl[w*512]);
    __syncthreads();
    bf16x8 ah[2], al[2], bh[4], bl[4];
#pragma unroll
    for (int i = 0; i < 2; ++i) {
      ah[i] = *(const bf16x8*)&sAh[((2*w + i)*64 + lane)*8];
      al[i] = *(const bf16x8*)&sAl[((2*w + i)*64 + lane)*8];
    }
#pragma unroll
    for (int n = 0; n < 4; ++n) {
      bh[n] = *(const bf16x8*)&sBh[(n*64 + lane)*8];
      bl[n] = *(const bf16x8*)&sBl[(n*64 + lane)*8];
    }
#pragma unroll
    for (int mi = 0; mi < 2; ++mi)
#pragma unroll
      for (int n = 0; n < 4; ++n) {
        acc[mi][n] = mfma16(ah[mi], bh[n], acc[mi][n]);
        acc[mi][n] = mfma16(ah[mi], bl[n], acc[mi][n]);
        acc[mi][n] = mfma16(al[mi], bh[n], acc[mi][n]);
      }
  }

  const int cr = (lane >> 4) * 4;
  const int cc = lane & 15;
#pragma unroll
  for (int mi = 0; mi < 2; ++mi)
#pragma unroll
    for (int n = 0; n < 4; ++n)
#pragma unroll
      for (int r = 0; r < 4; ++r)
        dtraw[(bm + 2*w*16 + mi*16 + cr + r) * 64 + n*16 + cc] = acc[mi][n][r];
}

// ---------------- causal conv1d (K=4) + SiLU, split x/B/C ----------------
__global__ __launch_bounds__(256)
void conv_kernel(const bf16_t* __restrict__ xbc, const float* __restrict__ cw,
                 const float* __restrict__ cb, bf16_t* __restrict__ xo,
                 bf16_t* __restrict__ Bout, bf16_t* __restrict__ Cout) {
  const int c = blockIdx.x * 256 + threadIdx.x;
  const int t0 = blockIdx.y * 8;
  const int bstart = (t0 >> 12) << 12;
  const float w0 = cw[c*4+0], w1 = cw[c*4+1], w2 = cw[c*4+2], w3 = cw[c*4+3];
  const float bias = cb[c];
  float in[11];
#pragma unroll
  for (int k = 0; k < 11; ++k) {
    int t = t0 - 3 + k;
    in[k] = (t >= bstart) ? (float)xbc[(size_t)t * XBCN + c] : 0.f;
  }
#pragma unroll
  for (int i = 0; i < 8; ++i) {
    float v = bias + w0*in[i] + w1*in[i+1] + w2*in[i+2] + w3*in[i+3];
    float s = v / (1.f + __expf(-v));
    int t = t0 + i;
    bf16_t o = (bf16_t)s;
    if (c < DINNER)           xo[(size_t)t * DINNER + c] = o;
    else if (c < DINNER+128)  Bout[(size_t)t * DSTATE + (c - DINNER)] = o;
    else                      Cout[(size_t)t * DSTATE + (c - DINNER - 128)] = o;
  }
}

// ---------------- softplus(dt)+cumsum(dA) per (b,chunk,head) ----------------
__global__ __launch_bounds__(256)
void dt_scan_kernel(const float* __restrict__ dtraw, const float* __restrict__ dt_bias,
                    const float* __restrict__ Avec, float* __restrict__ dt_s,
                    float* __restrict__ dAcs, float* __restrict__ cdec) {
  const int wid = blockIdx.x * 4 + (threadIdx.x >> 6);
  const int lane = threadIdx.x & 63;
  const int h = wid & 63;
  const int bc = wid >> 6;
  const long tok0 = (long)bc * 128;
  const float Ah = Avec[h];
  const float bias = dt_bias[h];
  float v0 = dtraw[(tok0 + lane)*64 + h] + bias;
  float v1 = dtraw[(tok0 + 64 + lane)*64 + h] + bias;
  float d0 = (v0 > 20.f) ? v0 : log1pf(expf(v0));
  float d1 = (v1 > 20.f) ? v1 : log1pf(expf(v1));
  float s0 = d0 * Ah;
  float s1 = d1 * Ah;
#pragma unroll
  for (int off = 1; off < 64; off <<= 1) {
    float t = __shfl_up(s0, off);
    if (lane >= off) s0 += t;
  }
  float tot0 = __shfl(s0, 63);
#pragma unroll
  for (int off = 1; off < 64; off <<= 1) {
    float t = __shfl_up(s1, off);
    if (lane >= off) s1 += t;
  }
  s1 += tot0;
  const size_t base = (size_t)wid * 128;
  dt_s[base + lane] = d0;
  dt_s[base + 64 + lane] = d1;
  dAcs[base + lane] = s0;
  dAcs[base + 64 + lane] = s1;
  if (lane == 63) cdec[wid] = __expf(s1);
}

// ---------------- per-chunk states: dtx^T @ (decay .* Bm) -> (64 x 128) bf16 ----------------
__global__ __launch_bounds__(256)
void states_kernel(const bf16_t* __restrict__ x, const bf16_t* __restrict__ Bm,
                   const float* __restrict__ dt_s, const float* __restrict__ dAcs,
                   bf16_t* __restrict__ states) {
  __shared__ bf16_t sDtx[8192];
  __shared__ bf16_t sBd[16384];
  __shared__ float sDt[128];
  __shared__ float sDec[128];
  const int wid = blockIdx.x;
  const int h = wid & 63;
  const int bc = wid >> 6;
  const int tid = threadIdx.x;
  const int lane = tid & 63;
  const int w = tid >> 6;
  const long tok0 = (long)bc * 128;
  const size_t dbase = (size_t)wid * 128;

  if (tid < 128) {
    sDt[tid] = dt_s[dbase + tid];
  } else {
    int j = tid - 128;
    sDec[j] = __expf(dAcs[dbase + 127] - dAcs[dbase + j]);
  }
  __syncthreads();

  {
    const int jj0 = tid >> 3;
    const int pg = (tid & 7) * 8;
#pragma unroll
    for (int t = 0; t < 4; ++t) {
      int j = t*32 + jj0;
      bf16x8 xv = *(const bf16x8*)&x[(tok0 + j)*(long)DINNER + h*64 + pg];
      float dtj = sDt[j];
      int kq = (j >> 5) * 4;
      int qe = ((j >> 3) & 3) * 16;
      int e = j & 7;
#pragma unroll
      for (int i = 0; i < 8; ++i) {
        int p = pg + i;
        sDtx[((kq + (p>>4))*64 + qe + (p&15))*8 + e] = (bf16_t)((float)xv[i]*dtj);
      }
    }
    const int jj1 = tid >> 4;
    const int ng = (tid & 15) * 8;
#pragma unroll
    for (int t = 0; t < 8; ++t) {
      int j = t*16 + jj1;
      bf16x8 bv = *(const bf16x8*)&Bm[(tok0 + j)*(long)DSTATE + ng];
      float dec = sDec[j];
      int kq = (j >> 5) * 8;
      int qe = ((j >> 3) & 3) * 16;
      int e = j & 7;
#pragma unroll
      for (int i = 0; i < 8; ++i) {
        int n = ng + i;
        sBd[((kq + (n>>4))*64 + qe + (n&15))*8 + e] = (bf16_t)((float)bv[i]*dec);
      }
    }
  }
  __syncthreads();

  f32x4 acc[4][2] = {};
#pragma unroll
  for (int kt = 0; kt < 4; ++kt) {
    bf16x8 aF[4], bF[2];
#pragma unroll
    for (int mt = 0; mt < 4; ++mt) aF[mt] = *(const bf16x8*)&sDtx[((kt*4 + mt)*64 + lane)*8];
#pragma unroll
    for (int nt = 0; nt < 2; ++nt) bF[nt] = *(const bf16x8*)&sBd[((kt*8 + w*2 + nt)*64 + lane)*8];
#pragma unroll
    for (int mt = 0; mt < 4; ++mt)
#pragma unroll
      for (int nt = 0; nt < 2; ++nt)
        acc[mt][nt] = mfma16(aF[mt], bF[nt], acc[mt][nt]);
  }

  bf16_t* S = states + (size_t)wid * (HD * DSTATE);
  const int cr = (lane >> 4) * 4;
  const int cc = lane & 15;
#pragma unroll
  for (int mt = 0; mt < 4; ++mt)
#pragma unroll
    for (int nt = 0; nt < 2; ++nt) {
      int n = (w*2 + nt)*16 + cc;
#pragma unroll
      for (int r = 0; r < 4; ++r) {
        int p = mt*16 + cr + r;
        S[(size_t)p*DSTATE + n] = (bf16_t)acc[mt][nt][r];
      }
    }
}

// ---------------- inter-chunk scan over 32 chunks (in-place: states -> prevs) ----------------
__global__ __launch_bounds__(256)
void scan_kernel(bf16_t* __restrict__ sp, const float* __restrict__ cdec) {
  const size_t gid = (size_t)blockIdx.x * 256 + threadIdx.x;
  const int n = gid & 127;
  const int p = (gid >> 7) & 63;
  const int h = (gid >> 13) & 63;
  const int b = (int)(gid >> 19);
  float prev = 0.f;
  const size_t pn = (size_t)p * 128 + n;
  for (int c = 0; c < 32; ++c) {
    const int wid = (b*32 + c)*64 + h;
    const size_t idx = (size_t)wid * 8192 + pn;
    float s = (float)sp[idx];
    sp[idx] = (bf16_t)prev;
    prev = cdec[wid] * prev + s;
  }
}

// ---------------- per-chunk Y: inter + intra + D*x (in-place over x) ----------------
__global__ __launch_bounds__(256)
void ssd_y_kernel(bf16_t* __restrict__ xy, const bf16_t* __restrict__ Bm,
                  const bf16_t* __restrict__ Cm, const bf16_t* __restrict__ prevs,
                  const float* __restrict__ dt_s, const float* __restrict__ dAcs,
                  const float* __restrict__ Dvec) {
  __shared__ bf16_t sG[16384];
  __shared__ bf16_t sDtx[8192];
  __shared__ float sDA[128];
  __shared__ float sEA[128];
  __shared__ float sDt[128];

  const int wid = blockIdx.x;
  const int h = wid & 63;
  const int bc = wid >> 6;
  const int tid = threadIdx.x;
  const int lane = tid & 63;
  const int w = tid >> 6;
  const long tok0 = (long)bc * 128;
  const size_t dbase = (size_t)wid * 128;

  if (tid < 128) {
    float v = dAcs[dbase + tid];
    sDA[tid] = v;
    sEA[tid] = __expf(v);
  } else {
    sDt[tid - 128] = dt_s[dbase + tid - 128];
  }
  __syncthreads();

  {
    const int jj0 = tid >> 3;
    const int pg = (tid & 7) * 8;
#pragma unroll
    for (int t = 0; t < 4; ++t) {
      int j = t*32 + jj0;
      bf16x8 xv = *(const bf16x8*)&xy[(tok0 + j)*(long)DINNER + h*64 + pg];
      float dtj = sDt[j];
      int kq = (j >> 5) * 4;
      int qe = ((j >> 3) & 3) * 16;
      int e = j & 7;
#pragma unroll
      for (int i = 0; i < 8; ++i) {
        int p = pg + i;
        sDtx[((kq + (p>>4))*64 + qe + (p&15))*8 + e] = (bf16_t)((float)xv[i]*dtj);
      }
    }
  }

  const int arow = (w*2)*16 + (lane & 15);
  const int koff = (lane >> 4) * 8;
  bf16x8 aCm[2][4];
#pragma unroll
  for (int mi = 0; mi < 2; ++mi)
#pragma unroll
    for (int kt = 0; kt < 4; ++kt)
      aCm[mi][kt] = *(const bf16x8*)&Cm[(tok0 + arow + mi*16)*(long)DSTATE + kt*32 + koff];

  const bf16_t* P = prevs + (size_t)wid * 8192;
  f32x4 accY[2][4] = {};
#pragma unroll
  for (int kt = 0; kt < 4; ++kt) {
    bf16x8 bP[4];
#pragma unroll
    for (int ni = 0; ni < 4; ++ni)
      bP[ni] = *(const bf16x8*)&P[(size_t)(ni*16 + (lane & 15))*DSTATE + kt*32 + koff];
#pragma unroll
    for (int mi = 0; mi < 2; ++mi)
#pragma unroll
      for (int ni = 0; ni < 4; ++ni)
        accY[mi][ni] = mfma16(aCm[mi][kt], bP[ni], accY[mi][ni]);
  }
  const int cr = (lane >> 4) * 4;
  const int cc = lane & 15;
#pragma unroll
  for (int mi = 0; mi < 2; ++mi)
#pragma unroll
    for (int r = 0; r < 4; ++r) {
      float e = sEA[(w*2 + mi)*16 + cr + r];
#pragma unroll
      for (int ni = 0; ni < 4; ++ni) accY[mi][ni][r] *= e;
    }

  f32x4 accS[2][8] = {};
#pragma unroll
  for (int kt = 0; kt < 4; ++kt) {
    bf16x8 bB[8];
#pragma unroll
    for (int nt = 0; nt < 8; ++nt)
      bB[nt] = *(const bf16x8*)&Bm[(tok0 + nt*16 + (lane & 15))*(long)DSTATE + kt*32 + koff];
#pragma unroll
    for (int mi = 0; mi < 2; ++mi)
#pragma unroll
      for (int nt = 0; nt < 8; ++nt)
        accS[mi][nt] = mfma16(aCm[mi][kt], bB[nt], accS[mi][nt]);
  }

#pragma unroll
  for (int mi = 0; mi < 2; ++mi)
#pragma unroll
    for (int nt = 0; nt < 8; ++nt)
#pragma unroll
      for (int r = 0; r < 4; ++r) {
        int i = (w*2 + mi)*16 + cr + r;
        int j = nt*16 + cc;
        float g = (i >= j) ? accS[mi][nt][r] * __expf(sDA[i] - sDA[j]) : 0.f;
        sG[(((j>>5)*8 + (i>>4))*64 + ((j>>3)&3)*16 + (i&15))*8 + (j&7)] = (bf16_t)g;
      }
  __syncthreads();

#pragma unroll
  for (int kt = 0; kt < 4; ++kt) {
    bf16x8 aG[2], bD[4];
#pragma unroll
    for (int mi = 0; mi < 2; ++mi) aG[mi] = *(const bf16x8*)&sG[((kt*8 + w*2 + mi)*64 + lane)*8];
#pragma unroll
    for (int ni = 0; ni < 4; ++ni) bD[ni] = *(const bf16x8*)&sDtx[((kt*4 + ni)*64 + lane)*8];
#pragma unroll
    for (int mi = 0; mi < 2; ++mi)
#pragma unroll
      for (int ni = 0; ni < 4; ++ni)
        accY[mi][ni] = mfma16(aG[mi], bD[ni], accY[mi][ni]);
  }

  const float Dh = Dvec[h];
#pragma unroll
  for (int mi = 0; mi < 2; ++mi)
#pragma unroll
    for (int ni = 0; ni < 4; ++ni)
#pragma unroll
      for (int r = 0; r < 4; ++r) {
        long tokr = tok0 + (w*2 + mi)*16 + cr + r;
        int p = ni*16 + cc;
        long idx = tokr * DINNER + h*64 + p;
        float xv = (float)xy[idx];
        xy[idx] = (bf16_t)(accY[mi][ni][r] + Dh * xv);
      }
}

// ---------------- gating + RMS norm ----------------
__global__ __launch_bounds__(256)
void gate_kernel(const bf16_t* __restrict__ y, const bf16_t* __restrict__ z,
                 const float* __restrict__ norm_w, bf16_t* __restrict__ yn) {
  const int tok = blockIdx.x;
  const int tid = threadIdx.x;
  const int lane = tid & 63;
  const int w = tid >> 6;
  const bf16_t* yrow = y + (size_t)tok * DINNER;
  const bf16_t* zrow = z + (size_t)tok * DINNER;
  float local[16];
  float ss = 0.f;
#pragma unroll
  for (int v = 0; v < 2; ++v) {
    int col = tid*16 + v*8;
    bf16x8 yv = *(const bf16x8*)&yrow[col];
    bf16x8 zv = *(const bf16x8*)&zrow[col];
#pragma unroll
    for (int i = 0; i < 8; ++i) {
      float zf = (float)zv[i];
      float g = zf / (1.f + __expf(-zf));
      float t = (float)yv[i] * g;
      local[v*8 + i] = t;
      ss += t*t;
    }
  }
#pragma unroll
  for (int off = 32; off > 0; off >>= 1) ss += __shfl_xor(ss, off);
  __shared__ float red[4];
  if (lane == 0) red[w] = ss;
  __syncthreads();
  float rms = rsqrtf((red[0]+red[1]+red[2]+red[3]) * (1.f/DINNER) + 1e-5f);
  bf16_t* orow = yn + (size_t)tok * DINNER;
#pragma unroll
  for (int v = 0; v < 2; ++v) {
    int col = tid*16 + v*8;
    bf16x8 o;
#pragma unroll
    for (int i = 0; i < 8; ++i) o[i] = (bf16_t)(local[v*8+i] * rms * norm_w[col+i]);
    *(bf16x8*)&orow[col] = o;
  }
}

// ---------------- launch ----------------
extern "C" void kernel_launch(void* const* d_in, const int* in_sizes, int n_in,
                              void* d_out, int out_size, void* d_ws, size_t ws_size,
                              hipStream_t stream) {
  const float* hidden  = (const float*)d_in[0];
  const float* W_in    = (const float*)d_in[1];
  const float* conv_w  = (const float*)d_in[2];
  const float* conv_b  = (const float*)d_in[3];
  const float* Avec    = (const float*)d_in[4];
  const float* Dvec    = (const float*)d_in[5];
  const float* dt_bias = (const float*)d_in[6];
  const float* norm_w  = (const float*)d_in[7];
  const float* W_out   = (const float*)d_in[8];

  char* ws = (char*)d_ws;
  size_t off = 0;
  auto take = [&](size_t bytes) -> char* {
    char* p = ws + off;
    off += (bytes + 255) & ~(size_t)255;
    return p;
  };
  bf16_t* R1    = (bf16_t*)take((size_t)NBC * NH * HD * DSTATE * 2);  // Xb -> states -> ynbuf
  bf16_t* WinT  = (bf16_t*)take((size_t)WINT_ROWS * DMODEL * 2);      // later WoutT
  bf16_t* xbc   = (bf16_t*)take((size_t)TOK * XBCN * 2);              // Xlo lives here first
  bf16_t* xconv = (bf16_t*)take((size_t)TOK * DINNER * 2);            // y in-place
  bf16_t* Bmat  = (bf16_t*)take((size_t)TOK * DSTATE * 2);
  bf16_t* Cmat  = (bf16_t*)take((size_t)TOK * DSTATE * 2);
  float*  dtraw = (float*)take((size_t)TOK * NH * 4);
  float*  dt_s  = (float*)take((size_t)TOK * NH * 4);
  float*  dAcs  = (float*)take((size_t)TOK * NH * 4);
  float*  cdec  = (float*)take((size_t)NBC * NH * 4);
  bf16_t* Wdth  = (bf16_t*)take((size_t)NH * DMODEL * 2);
  bf16_t* Wdtl  = (bf16_t*)take((size_t)NH * DMODEL * 2);
  if (off > ws_size) return;

  bf16_t* Xb      = R1;
  bf16_t* Xlo     = xbc;               // dead before xbc-gemm writes
  bf16_t* statesB = R1;
  bf16_t* ynbuf   = R1;
  bf16_t* WoutT   = WinT;
  bf16_t* zbuf    = (bf16_t*)d_out;    // z as bf16 in d_out
  float*  out     = (float*)d_out;

  cast_split_kernel<<<(TOK*DMODEL)/2048, 256, 0, stream>>>(hidden, Xb, Xlo, (size_t)TOK*DMODEL);
  wdt_split_kernel<<<DMODEL/256, 256, 0, stream>>>(W_in, Wdth, Wdtl);
  dt_mfma_kernel<<<TOK/128, 256, 0, stream>>>(Xb, Xlo, Wdth, Wdtl, dtraw);
  transpose_cast_kernel<<<dim3(WINT_ROWS/32, DMODEL/32), 256, 0, stream>>>(W_in, WinT, DMODEL, 8512, WINT_ROWS);
  // fused in-proj: cols [0,4096) -> zbuf, [4096,8448) -> xbc
  gemm256<bf16_t><<<(TOK/256)*(WINT_ROWS/256), 512, 0, stream>>>(
      Xb, WinT, zbuf, xbc, TOK, WINT_ROWS, DMODEL, DINNER, WINT_ROWS/256);
  transpose_cast_kernel<<<dim3(DMODEL/32, DINNER/32), 256, 0, stream>>>(W_out, WoutT, DINNER, DMODEL, DMODEL);
  conv_kernel<<<dim3(XBCN/256, TOK/8), 256, 0, stream>>>(xbc, conv_w, conv_b, xconv, Bmat, Cmat);
  dt_scan_kernel<<<(NBC*NH)/4, 256, 0, stream>>>(dtraw, dt_bias, Avec, dt_s, dAcs, cdec);
  states_kernel<<<NBC*NH, 256, 0, stream>>>(xconv, Bmat, dt_s, dAcs, statesB);
  scan_kernel<<<(NBC*NH*HD*DSTATE)/(32*256), 256, 0, stream>>>(statesB, cdec);
  ssd_y_kernel<<<NBC*NH, 256, 0, stream>>>(xconv, Bmat, Cmat, statesB, dt_s, dAcs, Dvec);
  gate_kernel<<<TOK, 256, 0, stream>>>(xconv, zbuf, norm_w, ynbuf);
  // out-proj
  gemm256<float><<<(TOK/256)*(DMODEL/256), 512, 0, stream>>>(
      ynbuf, WoutT, out, out, TOK, DMODEL, DINNER, DMODEL, DMODEL/256);
}

// Round 9
// 996.649 us; speedup vs baseline: 1.0565x; 1.0440x over previous
//
#include <hip/hip_runtime.h>
#include <hip/hip_bf16.h>

typedef __bf16 bf16_t;
typedef bf16_t bf16x8 __attribute__((ext_vector_type(8)));
typedef float f32x4 __attribute__((ext_vector_type(4)));

#define TOK 8192          // B*S
#define DMODEL 2048
#define DINNER 4096
#define XBCN 4352         // conv dim = 34*128
#define DSTATE 128
#define NH 64
#define HD 64
#define NBC 64            // B * (S/CHUNK) = 2*32
#define WINT_ROWS 8448    // z (4096) + xbc (4352)

// async global->LDS, 16B per lane, LDS dest = wave-uniform base + lane*16
__device__ __forceinline__ void gld16(const bf16_t* g, bf16_t* l) {
  __builtin_amdgcn_global_load_lds((const __attribute__((address_space(1))) void*)g,
                                   (__attribute__((address_space(3))) void*)l, 16, 0, 0);
}

__device__ __forceinline__ f32x4 mfma16(bf16x8 a, bf16x8 b, f32x4 c) {
  return __builtin_amdgcn_mfma_f32_16x16x32_bf16(a, b, c, 0, 0, 0);
}

// opaque LDS read (compiler cannot alias vs global_load_lds; we do counted waits)
__device__ __forceinline__ bf16x8 ldsr(unsigned addr) {
  f32x4 r;
  asm volatile("ds_read_b128 %0, %1" : "=v"(r) : "v"(addr));
  return __builtin_bit_cast(bf16x8, r);
}

// ---------------- utility kernels ----------------

__global__ __launch_bounds__(256)
void cast_split_kernel(const float* __restrict__ in, bf16_t* __restrict__ hi,
                       bf16_t* __restrict__ lo, size_t n) {
  size_t i = ((size_t)blockIdx.x * 256 + threadIdx.x) * 8;
  if (i + 8 > n) return;
  float4 a = *(const float4*)(in + i);
  float4 b = *(const float4*)(in + i + 4);
  float v[8] = {a.x,a.y,a.z,a.w,b.x,b.y,b.z,b.w};
  bf16x8 h, l;
#pragma unroll
  for (int j = 0; j < 8; ++j) {
    h[j] = (bf16_t)v[j];
    l[j] = (bf16_t)(v[j] - (float)h[j]);
  }
  *(bf16x8*)(hi + i) = h;
  *(bf16x8*)(lo + i) = l;
}

__global__ __launch_bounds__(256)
void transpose_cast_kernel(const float* __restrict__ in, bf16_t* __restrict__ out,
                           int R, int C, int outRows) {
  __shared__ float tile[32][33];
  const int c0 = blockIdx.x * 32;
  const int r0 = blockIdx.y * 32;
  const int tx = threadIdx.x & 31;
  const int ty = threadIdx.x >> 5;
#pragma unroll
  for (int k = 0; k < 4; ++k) {
    int r = r0 + ty + k*8;
    int c = c0 + tx;
    tile[ty + k*8][tx] = (c < C) ? in[(size_t)r * C + c] : 0.f;
  }
  __syncthreads();
#pragma unroll
  for (int k = 0; k < 4; ++k) {
    int oc = c0 + ty + k*8;
    int orr = r0 + tx;
    out[(size_t)oc * R + orr] = (bf16_t)tile[tx][ty + k*8];
  }
}

__global__ __launch_bounds__(256)
void wdt_split_kernel(const float* __restrict__ Win, bf16_t* __restrict__ Whi,
                      bf16_t* __restrict__ Wlo) {
  const int h = threadIdx.x & 63;
  const int k0 = blockIdx.x * 256 + (threadIdx.x >> 6) * 64;
#pragma unroll 4
  for (int i = 0; i < 64; ++i) {
    int k = k0 + i;
    float v = Win[(size_t)k * 8512 + 8448 + h];
    bf16_t hv = (bf16_t)v;
    Whi[(size_t)h * DMODEL + k] = hv;
    Wlo[(size_t)h * DMODEL + k] = (bf16_t)(v - (float)hv);
  }
}

// ---------------- 256x256 GEMM, m201-style 8-phase schedule ----------------
// 512 threads = 8 waves (2M x 4N), BK=64, 2 K-tiles per iteration, 128KB LDS.
// Per phase: {<=12 ds_read + 1 half-tile stage} -> barrier -> lgkmcnt(0) ->
// setprio(1) 16 MFMA setprio(0) -> barrier. vmcnt(6) ONLY at phases 4 & 8.
// Stage map (iter i, T=2i): ph1:Ah1(T+1) ph2:Ah0(T+2) ph3:Bh0(T+2) ph4:Bh1(T+2)
// ph5:Ah1(T+2) ph6:Ah0(T+3) ph7:Bh0(T+3) ph8:Bh1(T+3) — each region staged
// one-or-more closing-barriers after its last ds_read; vmcnt(6) retires exactly
// the 4 half-tiles the following 4 phases consume.
#define PH_MID() \
  __builtin_amdgcn_sched_barrier(0); \
  asm volatile("s_barrier" ::: "memory"); \
  asm volatile("s_waitcnt lgkmcnt(0)" ::: "memory"); \
  __builtin_amdgcn_sched_barrier(0); \
  __builtin_amdgcn_s_setprio(1)

#define PH_END() \
  __builtin_amdgcn_s_setprio(0); \
  __builtin_amdgcn_sched_barrier(0); \
  asm volatile("s_barrier" ::: "memory")

#define PH_END_VM6() \
  __builtin_amdgcn_s_setprio(0); \
  __builtin_amdgcn_sched_barrier(0); \
  asm volatile("s_waitcnt vmcnt(6)\n\ts_barrier" ::: "memory")

#define PH_END_VM0() \
  __builtin_amdgcn_s_setprio(0); \
  __builtin_amdgcn_sched_barrier(0); \
  asm volatile("s_waitcnt vmcnt(0)\n\ts_barrier" ::: "memory")

#define RD_A(arr, base) \
  _Pragma("unroll") \
  for (int mi = 0; mi < 4; ++mi) { \
    arr[mi][0] = ldsr((base) + (mi*2+0)*1024); \
    arr[mi][1] = ldsr((base) + (mi*2+1)*1024); \
  }

#define RD_B(arr, base) \
  _Pragma("unroll") \
  for (int ni = 0; ni < 2; ++ni) { \
    arr[ni][0] = ldsr((base) + (ni*2+0)*1024); \
    arr[ni][1] = ldsr((base) + (ni*2+1)*1024); \
  }

#define MMAQ(MB, NB, aa, bb2) \
  _Pragma("unroll") \
  for (int mi = 0; mi < 4; ++mi) \
    _Pragma("unroll") \
    for (int ni = 0; ni < 2; ++ni) { \
      acc[(MB)+mi][(NB)+ni] = mfma16(aa[mi][0], bb2[ni][0], acc[(MB)+mi][(NB)+ni]); \
      acc[(MB)+mi][(NB)+ni] = mfma16(aa[mi][1], bb2[ni][1], acc[(MB)+mi][(NB)+ni]); \
    }

template <typename OutT>
__global__ __launch_bounds__(512, 2)
void gemm256(const bf16_t* __restrict__ A, const bf16_t* __restrict__ B,
             OutT* __restrict__ C0, OutT* __restrict__ C1,
             long M, long N, long K, long splitN, int gridX) {
  __shared__ bf16_t sA[2][2][8192];   // [buf][half][(f*2+s)*512 + lane*8 + e]
  __shared__ bf16_t sB[2][2][8192];
  const int tid = threadIdx.x;
  const int lane = tid & 63;
  const int wid = tid >> 6;          // 0..7
  const int wr = wid >> 2;           // 0..1  (M)
  const int wc = wid & 3;            // 0..3  (N)

  // XCD chunk (contiguous, rows 4x..4x+3) iterated column-major for L2 reuse.
  const int x = blockIdx.x & 7;
  const int q = blockIdx.x >> 3;
  const long bm = (long)(x * 4 + (q & 3)) * 256;
  const long bn = (long)(q >> 2) * 256;

  // staging source mapping (fragment order): wave wid stages its slice
  const int srow = (wid >> 1) * 16 + (lane & 15);
  const int skof = (wid & 1) * 32 + (lane >> 4) * 8;
  const bf16_t* Abase = A + (bm + srow) * K + skof;
  const bf16_t* Bbase = B + (bn + srow) * K + skof;

  auto stageA = [&](int buf, int h, long kt) {
    const bf16_t* s = Abase + (long)h * 128 * K + kt;
    gld16(s,          &sA[buf][h][wid * 512]);
    gld16(s + 64 * K, &sA[buf][h][4096 + wid * 512]);
  };
  auto stageB = [&](int buf, int h, long kt) {
    const bf16_t* s = Bbase + (long)h * 128 * K + kt;
    gld16(s,          &sB[buf][h][wid * 512]);
    gld16(s + 64 * K, &sB[buf][h][4096 + wid * 512]);
  };

  const unsigned ldsA = (unsigned)(uintptr_t)(__attribute__((address_space(3))) void*)&sA[0][0][0]
                        + (unsigned)lane * 16 + (unsigned)wr * 8192;
  const unsigned ldsB = (unsigned)(uintptr_t)(__attribute__((address_space(3))) void*)&sB[0][0][0]
                        + (unsigned)lane * 16 + (unsigned)wc * 4096;
  const unsigned ab0 = ldsA;            // buf0 A-h0
  const unsigned ab0h = ldsA + 16384;   // buf0 A-h1
  const unsigned ab1 = ldsA + 32768;    // buf1 A-h0
  const unsigned ab1h = ldsA + 49152;   // buf1 A-h1
  const unsigned bb0 = ldsB;
  const unsigned bb0h = ldsB + 16384;
  const unsigned bb1 = ldsB + 32768;
  const unsigned bb1h = ldsB + 49152;

  // prologue: 7 half-tiles (14 loads): tile0 {Ah0,Bh0,Bh1,Ah1}, tile1 {Ah0,Bh0,Bh1}
  stageA(0, 0, 0); stageB(0, 0, 0); stageB(0, 1, 0); stageA(0, 1, 0);
  stageA(1, 0, 64); stageB(1, 0, 64); stageB(1, 1, 64);
  __builtin_amdgcn_sched_barrier(0);
  asm volatile("s_waitcnt vmcnt(6)\n\ts_barrier" ::: "memory");

  f32x4 acc[8][4] = {};
  bf16x8 a0[4][2], a1[4][2], b0[2][2], b1[2][2];
  const int NI = (int)(K >> 7);   // 2 K-tiles per iteration

  for (int i = 0; i < NI; ++i) {
    const bool fin = (i == NI - 1);
    const long k1 = ((long)(2*i + 1)) << 6;
    const long k2 = k1 + 64;
    const long k3 = k1 + 128;

    // ---- ph1: Q00(T) = a0 x b0 (buf0); stage Ah1(T+1)->buf1 ----
    RD_A(a0, ab0);
    RD_B(b0, bb0);
    stageA(1, 1, k1);
    PH_MID();
    MMAQ(0, 0, a0, b0);
    PH_END();

    // ---- ph2: Q01(T) = a0 x b1; stage Ah0(T+2)->buf0 ----
    RD_B(b1, bb0h);
    if (!fin) stageA(0, 0, k2);
    PH_MID();
    MMAQ(0, 2, a0, b1);
    PH_END();

    // ---- ph3: Q11(T) = a1 x b1; stage Bh0(T+2)->buf0 ----
    RD_A(a1, ab0h);
    if (!fin) stageB(0, 0, k2);
    PH_MID();
    MMAQ(4, 2, a1, b1);
    PH_END();

    // ---- ph4: Q10(T) = a1 x b0; stage Bh1(T+2)->buf0; vmcnt -> tile T+1 ready ----
    if (!fin) stageB(0, 1, k2);
    PH_MID();
    MMAQ(4, 0, a1, b0);
    if (!fin) { PH_END_VM6(); } else { PH_END_VM0(); }

    // ---- ph5: Q00(T+1) (buf1); stage Ah1(T+2)->buf0 ----
    RD_A(a0, ab1);
    RD_B(b0, bb1);
    if (!fin) stageA(0, 1, k2);
    PH_MID();
    MMAQ(0, 0, a0, b0);
    PH_END();

    // ---- ph6: Q01(T+1); stage Ah0(T+3)->buf1 ----
    RD_B(b1, bb1h);
    if (!fin) stageA(1, 0, k3);
    PH_MID();
    MMAQ(0, 2, a0, b1);
    PH_END();

    // ---- ph7: Q11(T+1); stage Bh0(T+3)->buf1 ----
    RD_A(a1, ab1h);
    if (!fin) stageB(1, 0, k3);
    PH_MID();
    MMAQ(4, 2, a1, b1);
    PH_END();

    // ---- ph8: Q10(T+1); stage Bh1(T+3)->buf1; vmcnt -> tile T+2 ready ----
    if (!fin) stageB(1, 1, k3);
    PH_MID();
    MMAQ(4, 0, a1, b0);
    if (!fin) { PH_END_VM6(); } else { PH_END(); }
  }

  // epilogue
  const int cr = (lane >> 4) * 4;
  const int cc = lane & 15;
  OutT* Cb;
  long col0, ldc;
  if (bn < splitN) { Cb = C0; col0 = bn; ldc = splitN; }
  else             { Cb = C1; col0 = bn - splitN; ldc = N - splitN; }
#pragma unroll
  for (int mi = 0; mi < 8; ++mi) {
    long row = bm + (mi >> 2) * 128 + wr * 64 + (mi & 3) * 16 + cr;
#pragma unroll
    for (int ni = 0; ni < 4; ++ni) {
      long col = col0 + (ni >> 1) * 128 + wc * 32 + (ni & 1) * 16 + cc;
      OutT* p = Cb + row * ldc + col;
#pragma unroll
      for (int r = 0; r < 4; ++r) p[(long)r * ldc] = (OutT)acc[mi][ni][r];
    }
  }
}

// ---------------- dt via split-bf16 MFMA: hi*hi + hi*lo + lo*hi ----------------
__global__ __launch_bounds__(256)
void dt_mfma_kernel(const bf16_t* __restrict__ Ahi, const bf16_t* __restrict__ Alo,
                    const bf16_t* __restrict__ Whi, const bf16_t* __restrict__ Wlo,
                    float* __restrict__ dtraw) {
  __shared__ bf16_t sAh[4096], sAl[4096], sBh[2048], sBl[2048];
  const int tid = threadIdx.x;
  const int lane = tid & 63;
  const int w = tid >> 6;
  const long bm = (long)blockIdx.x * 128;
  const int rlo = lane & 15;
  const int kq = lane >> 4;

  const bf16_t* Ah0 = Ahi + (bm + 2*w*16 + rlo) * (long)DMODEL + kq*8;
  const bf16_t* Ah1 = Ah0 + 16*(long)DMODEL;
  const bf16_t* Al0 = Alo + (bm + 2*w*16 + rlo) * (long)DMODEL + kq*8;
  const bf16_t* Al1 = Al0 + 16*(long)DMODEL;
  const bf16_t* Bh0 = Whi + (w*16 + rlo) * (long)DMODEL + kq*8;
  const bf16_t* Bl0 = Wlo + (w*16 + rlo) * (long)DMODEL + kq*8;

  f32x4 acc[2][4] = {};

  for (int kt = 0; kt < DMODEL; kt += 32) {
    __syncthreads();
    gld16(Ah0 + kt, &sAh[(2*w)*512]);
    gld16(Ah1 + kt, &sAh[(2*w+1)*512]);
    gld16(Al0 + kt, &sAl[(2*w)*512]);
    gld16(Al1 + kt, &sAl[(2*w+1)*512]);
    gld16(Bh0 + kt, &sBh[w*512]);
    gld16(Bl0 + kt, &sBl[w*512]);
    __syncthreads();
    bf16x8 ah[2], al[2], bh[4], bl[4];
#pragma unroll
    for (int i = 0; i < 2; ++i) {
      ah[i] = *(const bf16x8*)&sAh[((2*w + i)*64 + lane)*8];
      al[i] = *(const bf16x8*)&sAl[((2*w + i)*64 + lane)*8];
    }
#pragma unroll
    for (int n = 0; n < 4; ++n) {
      bh[n] = *(const bf16x8*)&sBh[(n*64 + lane)*8];
      bl[n] = *(const bf16x8*)&sBl[(n*64 + lane)*8];
    }
#pragma unroll
    for (int mi = 0; mi < 2; ++mi)
#pragma unroll
      for (int n = 0; n < 4; ++n) {
        acc[mi][n] = mfma16(ah[mi], bh[n], acc[mi][n]);
        acc[mi][n] = mfma16(ah[mi], bl[n], acc[mi][n]);
        acc[mi][n] = mfma16(al[mi], bh[n], acc[mi][n]);
      }
  }

  const int cr = (lane >> 4) * 4;
  const int cc = lane & 15;
#pragma unroll
  for (int mi = 0; mi < 2; ++mi)
#pragma unroll
    for (int n = 0; n < 4; ++n)
#pragma unroll
      for (int r = 0; r < 4; ++r)
        dtraw[(bm + 2*w*16 + mi*16 + cr + r) * 64 + n*16 + cc] = acc[mi][n][r];
}

// ---------------- causal conv1d (K=4) + SiLU, split x/B/C ----------------
__global__ __launch_bounds__(256)
void conv_kernel(const bf16_t* __restrict__ xbc, const float* __restrict__ cw,
                 const float* __restrict__ cb, bf16_t* __restrict__ xo,
                 bf16_t* __restrict__ Bout, bf16_t* __restrict__ Cout) {
  const int c = blockIdx.x * 256 + threadIdx.x;
  const int t0 = blockIdx.y * 8;
  const int bstart = (t0 >> 12) << 12;
  const float w0 = cw[c*4+0], w1 = cw[c*4+1], w2 = cw[c*4+2], w3 = cw[c*4+3];
  const float bias = cb[c];
  float in[11];
#pragma unroll
  for (int k = 0; k < 11; ++k) {
    int t = t0 - 3 + k;
    in[k] = (t >= bstart) ? (float)xbc[(size_t)t * XBCN + c] : 0.f;
  }
#pragma unroll
  for (int i = 0; i < 8; ++i) {
    float v = bias + w0*in[i] + w1*in[i+1] + w2*in[i+2] + w3*in[i+3];
    float s = v / (1.f + __expf(-v));
    int t = t0 + i;
    bf16_t o = (bf16_t)s;
    if (c < DINNER)           xo[(size_t)t * DINNER + c] = o;
    else if (c < DINNER+128)  Bout[(size_t)t * DSTATE + (c - DINNER)] = o;
    else                      Cout[(size_t)t * DSTATE + (c - DINNER - 128)] = o;
  }
}

// ---------------- softplus(dt)+cumsum(dA) per (b,chunk,head) ----------------
__global__ __launch_bounds__(256)
void dt_scan_kernel(const float* __restrict__ dtraw, const float* __restrict__ dt_bias,
                    const float* __restrict__ Avec, float* __restrict__ dt_s,
                    float* __restrict__ dAcs, float* __restrict__ cdec) {
  const int wid = blockIdx.x * 4 + (threadIdx.x >> 6);
  const int lane = threadIdx.x & 63;
  const int h = wid & 63;
  const int bc = wid >> 6;
  const long tok0 = (long)bc * 128;
  const float Ah = Avec[h];
  const float bias = dt_bias[h];
  float v0 = dtraw[(tok0 + lane)*64 + h] + bias;
  float v1 = dtraw[(tok0 + 64 + lane)*64 + h] + bias;
  float d0 = (v0 > 20.f) ? v0 : log1pf(expf(v0));
  float d1 = (v1 > 20.f) ? v1 : log1pf(expf(v1));
  float s0 = d0 * Ah;
  float s1 = d1 * Ah;
#pragma unroll
  for (int off = 1; off < 64; off <<= 1) {
    float t = __shfl_up(s0, off);
    if (lane >= off) s0 += t;
  }
  float tot0 = __shfl(s0, 63);
#pragma unroll
  for (int off = 1; off < 64; off <<= 1) {
    float t = __shfl_up(s1, off);
    if (lane >= off) s1 += t;
  }
  s1 += tot0;
  const size_t base = (size_t)wid * 128;
  dt_s[base + lane] = d0;
  dt_s[base + 64 + lane] = d1;
  dAcs[base + lane] = s0;
  dAcs[base + 64 + lane] = s1;
  if (lane == 63) cdec[wid] = __expf(s1);
}

// ---------------- per-chunk states: dtx^T @ (decay .* Bm) -> (64 x 128) bf16 ----------------
__global__ __launch_bounds__(256)
void states_kernel(const bf16_t* __restrict__ x, const bf16_t* __restrict__ Bm,
                   const float* __restrict__ dt_s, const float* __restrict__ dAcs,
                   bf16_t* __restrict__ states) {
  __shared__ bf16_t sDtx[8192];
  __shared__ bf16_t sBd[16384];
  __shared__ float sDt[128];
  __shared__ float sDec[128];
  const int wid = blockIdx.x;
  const int h = wid & 63;
  const int bc = wid >> 6;
  const int tid = threadIdx.x;
  const int lane = tid & 63;
  const int w = tid >> 6;
  const long tok0 = (long)bc * 128;
  const size_t dbase = (size_t)wid * 128;

  if (tid < 128) {
    sDt[tid] = dt_s[dbase + tid];
  } else {
    int j = tid - 128;
    sDec[j] = __expf(dAcs[dbase + 127] - dAcs[dbase + j]);
  }
  __syncthreads();

  {
    const int jj0 = tid >> 3;
    const int pg = (tid & 7) * 8;
#pragma unroll
    for (int t = 0; t < 4; ++t) {
      int j = t*32 + jj0;
      bf16x8 xv = *(const bf16x8*)&x[(tok0 + j)*(long)DINNER + h*64 + pg];
      float dtj = sDt[j];
      int kq = (j >> 5) * 4;
      int qe = ((j >> 3) & 3) * 16;
      int e = j & 7;
#pragma unroll
      for (int i = 0; i < 8; ++i) {
        int p = pg + i;
        sDtx[((kq + (p>>4))*64 + qe + (p&15))*8 + e] = (bf16_t)((float)xv[i]*dtj);
      }
    }
    const int jj1 = tid >> 4;
    const int ng = (tid & 15) * 8;
#pragma unroll
    for (int t = 0; t < 8; ++t) {
      int j = t*16 + jj1;
      bf16x8 bv = *(const bf16x8*)&Bm[(tok0 + j)*(long)DSTATE + ng];
      float dec = sDec[j];
      int kq = (j >> 5) * 8;
      int qe = ((j >> 3) & 3) * 16;
      int e = j & 7;
#pragma unroll
      for (int i = 0; i < 8; ++i) {
        int n = ng + i;
        sBd[((kq + (n>>4))*64 + qe + (n&15))*8 + e] = (bf16_t)((float)bv[i]*dec);
      }
    }
  }
  __syncthreads();

  f32x4 acc[4][2] = {};
#pragma unroll
  for (int kt = 0; kt < 4; ++kt) {
    bf16x8 aF[4], bF[2];
#pragma unroll
    for (int mt = 0; mt < 4; ++mt) aF[mt] = *(const bf16x8*)&sDtx[((kt*4 + mt)*64 + lane)*8];
#pragma unroll
    for (int nt = 0; nt < 2; ++nt) bF[nt] = *(const bf16x8*)&sBd[((kt*8 + w*2 + nt)*64 + lane)*8];
#pragma unroll
    for (int mt = 0; mt < 4; ++mt)
#pragma unroll
      for (int nt = 0; nt < 2; ++nt)
        acc[mt][nt] = mfma16(aF[mt], bF[nt], acc[mt][nt]);
  }

  bf16_t* S = states + (size_t)wid * (HD * DSTATE);
  const int cr = (lane >> 4) * 4;
  const int cc = lane & 15;
#pragma unroll
  for (int mt = 0; mt < 4; ++mt)
#pragma unroll
    for (int nt = 0; nt < 2; ++nt) {
      int n = (w*2 + nt)*16 + cc;
#pragma unroll
      for (int r = 0; r < 4; ++r) {
        int p = mt*16 + cr + r;
        S[(size_t)p*DSTATE + n] = (bf16_t)acc[mt][nt][r];
      }
    }
}

// ---------------- inter-chunk scan over 32 chunks (in-place: states -> prevs) ----------------
__global__ __launch_bounds__(256)
void scan_kernel(bf16_t* __restrict__ sp, const float* __restrict__ cdec) {
  const size_t gid = (size_t)blockIdx.x * 256 + threadIdx.x;
  const int n = gid & 127;
  const int p = (gid >> 7) & 63;
  const int h = (gid >> 13) & 63;
  const int b = (int)(gid >> 19);
  float prev = 0.f;
  const size_t pn = (size_t)p * 128 + n;
  for (int c = 0; c < 32; ++c) {
    const int wid = (b*32 + c)*64 + h;
    const size_t idx = (size_t)wid * 8192 + pn;
    float s = (float)sp[idx];
    sp[idx] = (bf16_t)prev;
    prev = cdec[wid] * prev + s;
  }
}

// ---------------- per-chunk Y: inter + intra + D*x (in-place over x) ----------------
__global__ __launch_bounds__(256)
void ssd_y_kernel(bf16_t* __restrict__ xy, const bf16_t* __restrict__ Bm,
                  const bf16_t* __restrict__ Cm, const bf16_t* __restrict__ prevs,
                  const float* __restrict__ dt_s, const float* __restrict__ dAcs,
                  const float* __restrict__ Dvec) {
  __shared__ bf16_t sG[16384];
  __shared__ bf16_t sDtx[8192];
  __shared__ float sDA[128];
  __shared__ float sEA[128];
  __shared__ float sDt[128];

  const int wid = blockIdx.x;
  const int h = wid & 63;
  const int bc = wid >> 6;
  const int tid = threadIdx.x;
  const int lane = tid & 63;
  const int w = tid >> 6;
  const long tok0 = (long)bc * 128;
  const size_t dbase = (size_t)wid * 128;

  if (tid < 128) {
    float v = dAcs[dbase + tid];
    sDA[tid] = v;
    sEA[tid] = __expf(v);
  } else {
    sDt[tid - 128] = dt_s[dbase + tid - 128];
  }
  __syncthreads();

  {
    const int jj0 = tid >> 3;
    const int pg = (tid & 7) * 8;
#pragma unroll
    for (int t = 0; t < 4; ++t) {
      int j = t*32 + jj0;
      bf16x8 xv = *(const bf16x8*)&xy[(tok0 + j)*(long)DINNER + h*64 + pg];
      float dtj = sDt[j];
      int kq = (j >> 5) * 4;
      int qe = ((j >> 3) & 3) * 16;
      int e = j & 7;
#pragma unroll
      for (int i = 0; i < 8; ++i) {
        int p = pg + i;
        sDtx[((kq + (p>>4))*64 + qe + (p&15))*8 + e] = (bf16_t)((float)xv[i]*dtj);
      }
    }
  }

  const int arow = (w*2)*16 + (lane & 15);
  const int koff = (lane >> 4) * 8;
  bf16x8 aCm[2][4];
#pragma unroll
  for (int mi = 0; mi < 2; ++mi)
#pragma unroll
    for (int kt = 0; kt < 4; ++kt)
      aCm[mi][kt] = *(const bf16x8*)&Cm[(tok0 + arow + mi*16)*(long)DSTATE + kt*32 + koff];

  const bf16_t* P = prevs + (size_t)wid * 8192;
  f32x4 accY[2][4] = {};
#pragma unroll
  for (int kt = 0; kt < 4; ++kt) {
    bf16x8 bP[4];
#pragma unroll
    for (int ni = 0; ni < 4; ++ni)
      bP[ni] = *(const bf16x8*)&P[(size_t)(ni*16 + (lane & 15))*DSTATE + kt*32 + koff];
#pragma unroll
    for (int mi = 0; mi < 2; ++mi)
#pragma unroll
      for (int ni = 0; ni < 4; ++ni)
        accY[mi][ni] = mfma16(aCm[mi][kt], bP[ni], accY[mi][ni]);
  }
  const int cr = (lane >> 4) * 4;
  const int cc = lane & 15;
#pragma unroll
  for (int mi = 0; mi < 2; ++mi)
#pragma unroll
    for (int r = 0; r < 4; ++r) {
      float e = sEA[(w*2 + mi)*16 + cr + r];
#pragma unroll
      for (int ni = 0; ni < 4; ++ni) accY[mi][ni][r] *= e;
    }

  f32x4 accS[2][8] = {};
#pragma unroll
  for (int kt = 0; kt < 4; ++kt) {
    bf16x8 bB[8];
#pragma unroll
    for (int nt = 0; nt < 8; ++nt)
      bB[nt] = *(const bf16x8*)&Bm[(tok0 + nt*16 + (lane & 15))*(long)DSTATE + kt*32 + koff];
#pragma unroll
    for (int mi = 0; mi < 2; ++mi)
#pragma unroll
      for (int nt = 0; nt < 8; ++nt)
        accS[mi][nt] = mfma16(aCm[mi][kt], bB[nt], accS[mi][nt]);
  }

#pragma unroll
  for (int mi = 0; mi < 2; ++mi)
#pragma unroll
    for (int nt = 0; nt < 8; ++nt)
#pragma unroll
      for (int r = 0; r < 4; ++r) {
        int i = (w*2 + mi)*16 + cr + r;
        int j = nt*16 + cc;
        float g = (i >= j) ? accS[mi][nt][r] * __expf(sDA[i] - sDA[j]) : 0.f;
        sG[(((j>>5)*8 + (i>>4))*64 + ((j>>3)&3)*16 + (i&15))*8 + (j&7)] = (bf16_t)g;
      }
  __syncthreads();

#pragma unroll
  for (int kt = 0; kt < 4; ++kt) {
    bf16x8 aG[2], bD[4];
#pragma unroll
    for (int mi = 0; mi < 2; ++mi) aG[mi] = *(const bf16x8*)&sG[((kt*8 + w*2 + mi)*64 + lane)*8];
#pragma unroll
    for (int ni = 0; ni < 4; ++ni) bD[ni] = *(const bf16x8*)&sDtx[((kt*4 + ni)*64 + lane)*8];
#pragma unroll
    for (int mi = 0; mi < 2; ++mi)
#pragma unroll
      for (int ni = 0; ni < 4; ++ni)
        accY[mi][ni] = mfma16(aG[mi], bD[ni], accY[mi][ni]);
  }

  const float Dh = Dvec[h];
#pragma unroll
  for (int mi = 0; mi < 2; ++mi)
#pragma unroll
    for (int ni = 0; ni < 4; ++ni)
#pragma unroll
      for (int r = 0; r < 4; ++r) {
        long tokr = tok0 + (w*2 + mi)*16 + cr + r;
        int p = ni*16 + cc;
        long idx = tokr * DINNER + h*64 + p;
        float xv = (float)xy[idx];
        xy[idx] = (bf16_t)(accY[mi][ni][r] + Dh * xv);
      }
}

// ---------------- gating + RMS norm ----------------
__global__ __launch_bounds__(256)
void gate_kernel(const bf16_t* __restrict__ y, const bf16_t* __restrict__ z,
                 const float* __restrict__ norm_w, bf16_t* __restrict__ yn) {
  const int tok = blockIdx.x;
  const int tid = threadIdx.x;
  const int lane = tid & 63;
  const int w = tid >> 6;
  const bf16_t* yrow = y + (size_t)tok * DINNER;
  const bf16_t* zrow = z + (size_t)tok * DINNER;
  float local[16];
  float ss = 0.f;
#pragma unroll
  for (int v = 0; v < 2; ++v) {
    int col = tid*16 + v*8;
    bf16x8 yv = *(const bf16x8*)&yrow[col];
    bf16x8 zv = *(const bf16x8*)&zrow[col];
#pragma unroll
    for (int i = 0; i < 8; ++i) {
      float zf = (float)zv[i];
      float g = zf / (1.f + __expf(-zf));
      float t = (float)yv[i] * g;
      local[v*8 + i] = t;
      ss += t*t;
    }
  }
#pragma unroll
  for (int off = 32; off > 0; off >>= 1) ss += __shfl_xor(ss, off);
  __shared__ float red[4];
  if (lane == 0) red[w] = ss;
  __syncthreads();
  float rms = rsqrtf((red[0]+red[1]+red[2]+red[3]) * (1.f/DINNER) + 1e-5f);
  bf16_t* orow = yn + (size_t)tok * DINNER;
#pragma unroll
  for (int v = 0; v < 2; ++v) {
    int col = tid*16 + v*8;
    bf16x8 o;
#pragma unroll
    for (int i = 0; i < 8; ++i) o[i] = (bf16_t)(local[v*8+i] * rms * norm_w[col+i]);
    *(bf16x8*)&orow[col] = o;
  }
}

// ---------------- launch ----------------
extern "C" void kernel_launch(void* const* d_in, const int* in_sizes, int n_in,
                              void* d_out, int out_size, void* d_ws, size_t ws_size,
                              hipStream_t stream) {
  const float* hidden  = (const float*)d_in[0];
  const float* W_in    = (const float*)d_in[1];
  const float* conv_w  = (const float*)d_in[2];
  const float* conv_b  = (const float*)d_in[3];
  const float* Avec    = (const float*)d_in[4];
  const float* Dvec    = (const float*)d_in[5];
  const float* dt_bias = (const float*)d_in[6];
  const float* norm_w  = (const float*)d_in[7];
  const float* W_out   = (const float*)d_in[8];

  char* ws = (char*)d_ws;
  size_t off = 0;
  auto take = [&](size_t bytes) -> char* {
    char* p = ws + off;
    off += (bytes + 255) & ~(size_t)255;
    return p;
  };
  bf16_t* R1    = (bf16_t*)take((size_t)NBC * NH * HD * DSTATE * 2);  // Xb -> states -> ynbuf
  bf16_t* WinT  = (bf16_t*)take((size_t)WINT_ROWS * DMODEL * 2);      // later WoutT
  bf16_t* xbc   = (bf16_t*)take((size_t)TOK * XBCN * 2);              // Xlo lives here first
  bf16_t* xconv = (bf16_t*)take((size_t)TOK * DINNER * 2);            // y in-place
  bf16_t* Bmat  = (bf16_t*)take((size_t)TOK * DSTATE * 2);
  bf16_t* Cmat  = (bf16_t*)take((size_t)TOK * DSTATE * 2);
  float*  dtraw = (float*)take((size_t)TOK * NH * 4);
  float*  dt_s  = (float*)take((size_t)TOK * NH * 4);
  float*  dAcs  = (float*)take((size_t)TOK * NH * 4);
  float*  cdec  = (float*)take((size_t)NBC * NH * 4);
  bf16_t* Wdth  = (bf16_t*)take((size_t)NH * DMODEL * 2);
  bf16_t* Wdtl  = (bf16_t*)take((size_t)NH * DMODEL * 2);
  if (off > ws_size) return;

  bf16_t* Xb      = R1;
  bf16_t* Xlo     = xbc;               // dead before xbc-gemm writes
  bf16_t* statesB = R1;
  bf16_t* ynbuf   = R1;
  bf16_t* WoutT   = WinT;
  bf16_t* zbuf    = (bf16_t*)d_out;    // z as bf16 in d_out
  float*  out     = (float*)d_out;

  cast_split_kernel<<<(TOK*DMODEL)/2048, 256, 0, stream>>>(hidden, Xb, Xlo, (size_t)TOK*DMODEL);
  wdt_split_kernel<<<DMODEL/256, 256, 0, stream>>>(W_in, Wdth, Wdtl);
  dt_mfma_kernel<<<TOK/128, 256, 0, stream>>>(Xb, Xlo, Wdth, Wdtl, dtraw);
  transpose_cast_kernel<<<dim3(WINT_ROWS/32, DMODEL/32), 256, 0, stream>>>(W_in, WinT, DMODEL, 8512, WINT_ROWS);
  // fused in-proj: cols [0,4096) -> zbuf, [4096,8448) -> xbc
  gemm256<bf16_t><<<(TOK/256)*(WINT_ROWS/256), 512, 0, stream>>>(
      Xb, WinT, zbuf, xbc, TOK, WINT_ROWS, DMODEL, DINNER, WINT_ROWS/256);
  transpose_cast_kernel<<<dim3(DMODEL/32, DINNER/32), 256, 0, stream>>>(W_out, WoutT, DINNER, DMODEL, DMODEL);
  conv_kernel<<<dim3(XBCN/256, TOK/8), 256, 0, stream>>>(xbc, conv_w, conv_b, xconv, Bmat, Cmat);
  dt_scan_kernel<<<(NBC*NH)/4, 256, 0, stream>>>(dtraw, dt_bias, Avec, dt_s, dAcs, cdec);
  states_kernel<<<NBC*NH, 256, 0, stream>>>(xconv, Bmat, dt_s, dAcs, statesB);
  scan_kernel<<<(NBC*NH*HD*DSTATE)/(32*256), 256, 0, stream>>>(statesB, cdec);
  ssd_y_kernel<<<NBC*NH, 256, 0, stream>>>(xconv, Bmat, Cmat, statesB, dt_s, dAcs, Dvec);
  gate_kernel<<<TOK, 256, 0, stream>>>(xconv, zbuf, norm_w, ynbuf);
  // out-proj
  gemm256<float><<<(TOK/256)*(DMODEL/256), 512, 0, stream>>>(
      ynbuf, WoutT, out, out, TOK, DMODEL, DINNER, DMODEL, DMODEL/256);
}

// Round 10
// 953.264 us; speedup vs baseline: 1.1046x; 1.0455x over previous
//
#include <hip/hip_runtime.h>
#include <hip/hip_bf16.h>

typedef __bf16 bf16_t;
typedef bf16_t bf16x8 __attribute__((ext_vector_type(8)));
typedef float f32x4 __attribute__((ext_vector_type(4)));

#define TOK 8192          // B*S
#define DMODEL 2048
#define DINNER 4096
#define XBCN 4352         // conv dim = 34*128
#define DSTATE 128
#define NH 64
#define HD 64
#define NBC 64            // B * (S/CHUNK) = 2*32
#define WINT_ROWS 8448    // z (4096) + xbc (4352)

// async global->LDS, 16B per lane, LDS dest = wave-uniform base + lane*16
__device__ __forceinline__ void gld16(const bf16_t* g, bf16_t* l) {
  __builtin_amdgcn_global_load_lds((const __attribute__((address_space(1))) void*)g,
                                   (__attribute__((address_space(3))) void*)l, 16, 0, 0);
}

__device__ __forceinline__ f32x4 mfma16(bf16x8 a, bf16x8 b, f32x4 c) {
  return __builtin_amdgcn_mfma_f32_16x16x32_bf16(a, b, c, 0, 0, 0);
}

// opaque LDS read (compiler cannot alias vs global_load_lds; we do counted waits)
__device__ __forceinline__ bf16x8 ldsr(unsigned addr) {
  f32x4 r;
  asm volatile("ds_read_b128 %0, %1" : "=v"(r) : "v"(addr));
  return __builtin_bit_cast(bf16x8, r);
}

// ---------------- utility kernels ----------------

__global__ __launch_bounds__(256)
void cast_split_kernel(const float* __restrict__ in, bf16_t* __restrict__ hi,
                       bf16_t* __restrict__ lo, size_t n) {
  size_t i = ((size_t)blockIdx.x * 256 + threadIdx.x) * 8;
  if (i + 8 > n) return;
  float4 a = *(const float4*)(in + i);
  float4 b = *(const float4*)(in + i + 4);
  float v[8] = {a.x,a.y,a.z,a.w,b.x,b.y,b.z,b.w};
  bf16x8 h, l;
#pragma unroll
  for (int j = 0; j < 8; ++j) {
    h[j] = (bf16_t)v[j];
    l[j] = (bf16_t)(v[j] - (float)h[j]);
  }
  *(bf16x8*)(hi + i) = h;
  *(bf16x8*)(lo + i) = l;
}

__global__ __launch_bounds__(256)
void transpose_cast_kernel(const float* __restrict__ in, bf16_t* __restrict__ out,
                           int R, int C, int outRows) {
  __shared__ float tile[32][33];
  const int c0 = blockIdx.x * 32;
  const int r0 = blockIdx.y * 32;
  const int tx = threadIdx.x & 31;
  const int ty = threadIdx.x >> 5;
#pragma unroll
  for (int k = 0; k < 4; ++k) {
    int r = r0 + ty + k*8;
    int c = c0 + tx;
    tile[ty + k*8][tx] = (c < C) ? in[(size_t)r * C + c] : 0.f;
  }
  __syncthreads();
#pragma unroll
  for (int k = 0; k < 4; ++k) {
    int oc = c0 + ty + k*8;
    int orr = r0 + tx;
    out[(size_t)oc * R + orr] = (bf16_t)tile[tx][ty + k*8];
  }
}

__global__ __launch_bounds__(256)
void wdt_split_kernel(const float* __restrict__ Win, bf16_t* __restrict__ Whi,
                      bf16_t* __restrict__ Wlo) {
  const int h = threadIdx.x & 63;
  const int k0 = blockIdx.x * 256 + (threadIdx.x >> 6) * 64;
#pragma unroll 4
  for (int i = 0; i < 64; ++i) {
    int k = k0 + i;
    float v = Win[(size_t)k * 8512 + 8448 + h];
    bf16_t hv = (bf16_t)v;
    Whi[(size_t)h * DMODEL + k] = hv;
    Wlo[(size_t)h * DMODEL + k] = (bf16_t)(v - (float)hv);
  }
}

// ---------------- 256x256 GEMM v10: cross-phase read-ahead + counted lgkm ----------------
// 512 threads = 8 waves (2M x 4N), BK=64, 128KB LDS double-buffered, fragment-order LDS.
// Per phase: reads for phase p were issued DURING phase p-1, so the wait is a counted
// lgkmcnt that is already covered by p-1's MFMA cluster. Progressive vmcnt(2) retires
// each staged half-tile exactly one barrier before the pre-read that consumes it.
// Quadrant order Q00(a0,b0) Q01(a0,b1) Q10(a1,b0) Q11(a1,b1); Q11's regs free a0,b0
// for the next-tile pre-read. Stage order per tile: P0:Ah0' P1:Bh0' P2:Bh1' P3:Ah1'.
#define RD_A(arr, base) \
  _Pragma("unroll") \
  for (int mi = 0; mi < 4; ++mi) { \
    arr[mi][0] = ldsr((base) + (mi*2+0)*1024); \
    arr[mi][1] = ldsr((base) + (mi*2+1)*1024); \
  }

#define RD_B(arr, base) \
  _Pragma("unroll") \
  for (int ni = 0; ni < 2; ++ni) { \
    arr[ni][0] = ldsr((base) + (ni*2+0)*1024); \
    arr[ni][1] = ldsr((base) + (ni*2+1)*1024); \
  }

#define MMAQ(MB, NB, aa, bb2) \
  _Pragma("unroll") \
  for (int mi = 0; mi < 4; ++mi) \
    _Pragma("unroll") \
    for (int ni = 0; ni < 2; ++ni) { \
      acc[(MB)+mi][(NB)+ni] = mfma16(aa[mi][0], bb2[ni][0], acc[(MB)+mi][(NB)+ni]); \
      acc[(MB)+mi][(NB)+ni] = mfma16(aa[mi][1], bb2[ni][1], acc[(MB)+mi][(NB)+ni]); \
    }

#define SBAR() __builtin_amdgcn_sched_barrier(0)

template <typename OutT>
__global__ __launch_bounds__(512, 2)
void gemm256(const bf16_t* __restrict__ A, const bf16_t* __restrict__ B,
             OutT* __restrict__ C0, OutT* __restrict__ C1,
             long M, long N, long K, long splitN, int gridX) {
  __shared__ bf16_t sA[2][2][8192];   // [buf][half][(f*2+s)*512 + lane*8 + e]
  __shared__ bf16_t sB[2][2][8192];
  const int tid = threadIdx.x;
  const int lane = tid & 63;
  const int wid = tid >> 6;          // 0..7
  const int wr = wid >> 2;           // 0..1  (M)
  const int wc = wid & 3;            // 0..3  (N)

  // XCD chunk (contiguous, rows 4x..4x+3) iterated column-major for L2 reuse.
  const int x = blockIdx.x & 7;
  const int q = blockIdx.x >> 3;
  const long bm = (long)(x * 4 + (q & 3)) * 256;
  const long bn = (long)(q >> 2) * 256;

  // staging source mapping (fragment order): wave wid stages its slice
  const int srow = (wid >> 1) * 16 + (lane & 15);
  const int skof = (wid & 1) * 32 + (lane >> 4) * 8;
  const bf16_t* Abase = A + (bm + srow) * K + skof;
  const bf16_t* Bbase = B + (bn + srow) * K + skof;

  auto stageA = [&](int buf, int h, long kt) {
    const bf16_t* s = Abase + (long)h * 128 * K + kt;
    gld16(s,          &sA[buf][h][wid * 512]);
    gld16(s + 64 * K, &sA[buf][h][4096 + wid * 512]);
  };
  auto stageB = [&](int buf, int h, long kt) {
    const bf16_t* s = Bbase + (long)h * 128 * K + kt;
    gld16(s,          &sB[buf][h][wid * 512]);
    gld16(s + 64 * K, &sB[buf][h][4096 + wid * 512]);
  };

  const unsigned sAb = (unsigned)(uintptr_t)(__attribute__((address_space(3))) void*)&sA[0][0][0]
                       + (unsigned)lane * 16 + (unsigned)wr * 8192;
  const unsigned sBb = (unsigned)(uintptr_t)(__attribute__((address_space(3))) void*)&sB[0][0][0]
                       + (unsigned)lane * 16 + (unsigned)wc * 4096;

  // prologue: stage A0,B0(t0); drain; issue reads a0,b0; stage B1,A1(t0)
  stageA(0, 0, 0); stageB(0, 0, 0);
  SBAR();
  asm volatile("s_waitcnt vmcnt(0)\n\ts_barrier" ::: "memory");
  f32x4 acc[8][4] = {};
  bf16x8 a0[4][2], a1[4][2], b0[2][2], b1[2][2];
  RD_A(a0, sAb);
  RD_B(b0, sBb);
  stageB(0, 1, 0); stageA(0, 1, 0);
  SBAR();

  int cur = 0;
  const int NT = (int)(K >> 6);

  for (int t = 0; t < NT; ++t) {
    const bool fin = (t == NT - 1);
    const long ktn = (long)(t + 1) * 64;
    const unsigned ab  = sAb + (unsigned)cur * 32768;
    const unsigned bb  = sBb + (unsigned)cur * 32768;
    const unsigned abn = sAb + (unsigned)(cur ^ 1) * 32768;
    const unsigned bbn = sBb + (unsigned)(cur ^ 1) * 32768;

    // ---- P0 (Q00: a0 x b0); pre-read b1; stage Ah0' ----
    asm volatile("s_waitcnt vmcnt(2)\n\ts_barrier" ::: "memory");  // retires Bh1(t)
    if (!fin) stageA(cur ^ 1, 0, ktn);
    RD_B(b1, bb + 16384);
    asm volatile("s_waitcnt lgkmcnt(4)" ::: "memory");             // a0,b0 ready
    SBAR();
    __builtin_amdgcn_s_setprio(1);
    MMAQ(0, 0, a0, b0);
    __builtin_amdgcn_s_setprio(0);
    SBAR();

    // ---- P1 (Q01: a0 x b1); pre-read a1; stage Bh0' ----
    if (!fin) asm volatile("s_waitcnt vmcnt(2)\n\ts_barrier" ::: "memory"); // retires Ah1(t)
    else      asm volatile("s_waitcnt vmcnt(0)\n\ts_barrier" ::: "memory");
    if (!fin) stageB(cur ^ 1, 0, ktn);
    RD_A(a1, ab + 16384);
    asm volatile("s_waitcnt lgkmcnt(8)" ::: "memory");             // b1 ready
    SBAR();
    __builtin_amdgcn_s_setprio(1);
    MMAQ(0, 2, a0, b1);
    __builtin_amdgcn_s_setprio(0);
    SBAR();

    // ---- P2 (Q10: a1 x b0); no pre-read; stage Bh1' ----
    asm volatile("s_barrier" ::: "memory");
    if (!fin) stageB(cur ^ 1, 1, ktn);
    asm volatile("s_waitcnt lgkmcnt(0)" ::: "memory");             // a1 ready
    SBAR();
    __builtin_amdgcn_s_setprio(1);
    MMAQ(4, 0, a1, b0);
    __builtin_amdgcn_s_setprio(0);
    SBAR();

    // ---- P3 (Q11: a1 x b1); pre-read next a0,b0; stage Ah1' ----
    if (!fin) asm volatile("s_waitcnt vmcnt(2)\n\ts_barrier" ::: "memory"); // retires Ah0',Bh0'
    else      asm volatile("s_barrier" ::: "memory");
    if (!fin) {
      stageA(cur ^ 1, 1, ktn);
      RD_A(a0, abn);
      RD_B(b0, bbn);
    }
    SBAR();
    __builtin_amdgcn_s_setprio(1);
    MMAQ(4, 2, a1, b1);
    __builtin_amdgcn_s_setprio(0);
    SBAR();
    cur ^= 1;
  }

  // epilogue
  const int cr = (lane >> 4) * 4;
  const int cc = lane & 15;
  OutT* Cb;
  long col0, ldc;
  if (bn < splitN) { Cb = C0; col0 = bn; ldc = splitN; }
  else             { Cb = C1; col0 = bn - splitN; ldc = N - splitN; }
#pragma unroll
  for (int mi = 0; mi < 8; ++mi) {
    long row = bm + (mi >> 2) * 128 + wr * 64 + (mi & 3) * 16 + cr;
#pragma unroll
    for (int ni = 0; ni < 4; ++ni) {
      long col = col0 + (ni >> 1) * 128 + wc * 32 + (ni & 1) * 16 + cc;
      OutT* p = Cb + row * ldc + col;
#pragma unroll
      for (int r = 0; r < 4; ++r) p[(long)r * ldc] = (OutT)acc[mi][ni][r];
    }
  }
}

// ---------------- dt via split-bf16 MFMA (M=32 tile, 256 blocks, 8 waves) ----------------
// dtraw = Xhi@(Whi+Wlo)^T + Xlo@Whi^T, f32 accum. 2-phase double-buffered staging.
__global__ __launch_bounds__(512)
void dt_mfma_kernel(const bf16_t* __restrict__ Ahi, const bf16_t* __restrict__ Alo,
                    const bf16_t* __restrict__ Whi, const bf16_t* __restrict__ Wlo,
                    float* __restrict__ dtraw) {
  __shared__ bf16_t sb[2][6144];   // [Ah f0,f1 | Al f0,f1 | Bh f0..3 | Bl f0..3] x 512 bf16
  const int tid = threadIdx.x;
  const int lane = tid & 63;
  const int w = tid >> 6;           // 0..7
  const long bm = (long)blockIdx.x * 32;
  const int rlo = lane & 15;
  const int kq = lane >> 4;
  const long K = DMODEL;

  const bf16_t* srcA  = (w < 2 ? Ahi : Alo) + (bm + (w & 1) * 16 + rlo) * K + kq * 8;
  const bf16_t* srcBl = Wlo + ((w & 3) * 16 + rlo) * K + kq * 8;
  const bf16_t* srcBh = Whi + (((w - 4) & 3) * 16 + rlo) * K + kq * 8;

  auto stage = [&](int b, long kt) {
    if (w < 4) {
      gld16(srcA + kt,  &sb[b][w * 512]);
      gld16(srcBl + kt, &sb[b][4096 + w * 512]);
    } else {
      gld16(srcBh + kt, &sb[b][2048 + (w - 4) * 512]);
    }
  };

  const int mfrag = w >> 2;   // 0..1
  const int nfrag = w & 3;    // 0..3
  f32x4 acc = {};
  stage(0, 0);
  __syncthreads();
  int cur = 0;
  for (long kt = 0; kt < K; kt += 32) {
    if (kt + 32 < K) stage(cur ^ 1, kt + 32);
    bf16x8 ah = *(const bf16x8*)&sb[cur][mfrag * 512 + lane * 8];
    bf16x8 al = *(const bf16x8*)&sb[cur][1024 + mfrag * 512 + lane * 8];
    bf16x8 bh = *(const bf16x8*)&sb[cur][2048 + nfrag * 512 + lane * 8];
    bf16x8 bl = *(const bf16x8*)&sb[cur][4096 + nfrag * 512 + lane * 8];
    acc = mfma16(ah, bh, acc);
    acc = mfma16(ah, bl, acc);
    acc = mfma16(al, bh, acc);
    __syncthreads();
    cur ^= 1;
  }
  const int cr = (lane >> 4) * 4;
  const int cc = lane & 15;
#pragma unroll
  for (int r = 0; r < 4; ++r)
    dtraw[(bm + mfrag * 16 + cr + r) * 64 + nfrag * 16 + cc] = acc[r];
}

// ---------------- causal conv1d (K=4) + SiLU, split x/B/C ----------------
__global__ __launch_bounds__(256)
void conv_kernel(const bf16_t* __restrict__ xbc, const float* __restrict__ cw,
                 const float* __restrict__ cb, bf16_t* __restrict__ xo,
                 bf16_t* __restrict__ Bout, bf16_t* __restrict__ Cout) {
  const int c = blockIdx.x * 256 + threadIdx.x;
  const int t0 = blockIdx.y * 8;
  const int bstart = (t0 >> 12) << 12;
  const float w0 = cw[c*4+0], w1 = cw[c*4+1], w2 = cw[c*4+2], w3 = cw[c*4+3];
  const float bias = cb[c];
  float in[11];
#pragma unroll
  for (int k = 0; k < 11; ++k) {
    int t = t0 - 3 + k;
    in[k] = (t >= bstart) ? (float)xbc[(size_t)t * XBCN + c] : 0.f;
  }
#pragma unroll
  for (int i = 0; i < 8; ++i) {
    float v = bias + w0*in[i] + w1*in[i+1] + w2*in[i+2] + w3*in[i+3];
    float s = v / (1.f + __expf(-v));
    int t = t0 + i;
    bf16_t o = (bf16_t)s;
    if (c < DINNER)           xo[(size_t)t * DINNER + c] = o;
    else if (c < DINNER+128)  Bout[(size_t)t * DSTATE + (c - DINNER)] = o;
    else                      Cout[(size_t)t * DSTATE + (c - DINNER - 128)] = o;
  }
}

// ---------------- softplus(dt)+cumsum(dA) per (b,chunk,head) ----------------
__global__ __launch_bounds__(256)
void dt_scan_kernel(const float* __restrict__ dtraw, const float* __restrict__ dt_bias,
                    const float* __restrict__ Avec, float* __restrict__ dt_s,
                    float* __restrict__ dAcs, float* __restrict__ cdec) {
  const int wid = blockIdx.x * 4 + (threadIdx.x >> 6);
  const int lane = threadIdx.x & 63;
  const int h = wid & 63;
  const int bc = wid >> 6;
  const long tok0 = (long)bc * 128;
  const float Ah = Avec[h];
  const float bias = dt_bias[h];
  float v0 = dtraw[(tok0 + lane)*64 + h] + bias;
  float v1 = dtraw[(tok0 + 64 + lane)*64 + h] + bias;
  float d0 = (v0 > 20.f) ? v0 : log1pf(expf(v0));
  float d1 = (v1 > 20.f) ? v1 : log1pf(expf(v1));
  float s0 = d0 * Ah;
  float s1 = d1 * Ah;
#pragma unroll
  for (int off = 1; off < 64; off <<= 1) {
    float t = __shfl_up(s0, off);
    if (lane >= off) s0 += t;
  }
  float tot0 = __shfl(s0, 63);
#pragma unroll
  for (int off = 1; off < 64; off <<= 1) {
    float t = __shfl_up(s1, off);
    if (lane >= off) s1 += t;
  }
  s1 += tot0;
  const size_t base = (size_t)wid * 128;
  dt_s[base + lane] = d0;
  dt_s[base + 64 + lane] = d1;
  dAcs[base + lane] = s0;
  dAcs[base + 64 + lane] = s1;
  if (lane == 63) cdec[wid] = __expf(s1);
}

// ---------------- per-chunk states: dtx^T @ (decay .* Bm) -> (64 x 128) bf16 ----------------
__global__ __launch_bounds__(256)
void states_kernel(const bf16_t* __restrict__ x, const bf16_t* __restrict__ Bm,
                   const float* __restrict__ dt_s, const float* __restrict__ dAcs,
                   bf16_t* __restrict__ states) {
  __shared__ bf16_t sDtx[8192];
  __shared__ bf16_t sBd[16384];
  __shared__ float sDt[128];
  __shared__ float sDec[128];
  const int wid = blockIdx.x;
  const int h = wid & 63;
  const int bc = wid >> 6;
  const int tid = threadIdx.x;
  const int lane = tid & 63;
  const int w = tid >> 6;
  const long tok0 = (long)bc * 128;
  const size_t dbase = (size_t)wid * 128;

  if (tid < 128) {
    sDt[tid] = dt_s[dbase + tid];
  } else {
    int j = tid - 128;
    sDec[j] = __expf(dAcs[dbase + 127] - dAcs[dbase + j]);
  }
  __syncthreads();

  {
    const int jj0 = tid >> 3;
    const int pg = (tid & 7) * 8;
#pragma unroll
    for (int t = 0; t < 4; ++t) {
      int j = t*32 + jj0;
      bf16x8 xv = *(const bf16x8*)&x[(tok0 + j)*(long)DINNER + h*64 + pg];
      float dtj = sDt[j];
      int kq = (j >> 5) * 4;
      int qe = ((j >> 3) & 3) * 16;
      int e = j & 7;
#pragma unroll
      for (int i = 0; i < 8; ++i) {
        int p = pg + i;
        sDtx[((kq + (p>>4))*64 + qe + (p&15))*8 + e] = (bf16_t)((float)xv[i]*dtj);
      }
    }
    const int jj1 = tid >> 4;
    const int ng = (tid & 15) * 8;
#pragma unroll
    for (int t = 0; t < 8; ++t) {
      int j = t*16 + jj1;
      bf16x8 bv = *(const bf16x8*)&Bm[(tok0 + j)*(long)DSTATE + ng];
      float dec = sDec[j];
      int kq = (j >> 5) * 8;
      int qe = ((j >> 3) & 3) * 16;
      int e = j & 7;
#pragma unroll
      for (int i = 0; i < 8; ++i) {
        int n = ng + i;
        sBd[((kq + (n>>4))*64 + qe + (n&15))*8 + e] = (bf16_t)((float)bv[i]*dec);
      }
    }
  }
  __syncthreads();

  f32x4 acc[4][2] = {};
#pragma unroll
  for (int kt = 0; kt < 4; ++kt) {
    bf16x8 aF[4], bF[2];
#pragma unroll
    for (int mt = 0; mt < 4; ++mt) aF[mt] = *(const bf16x8*)&sDtx[((kt*4 + mt)*64 + lane)*8];
#pragma unroll
    for (int nt = 0; nt < 2; ++nt) bF[nt] = *(const bf16x8*)&sBd[((kt*8 + w*2 + nt)*64 + lane)*8];
#pragma unroll
    for (int mt = 0; mt < 4; ++mt)
#pragma unroll
      for (int nt = 0; nt < 2; ++nt)
        acc[mt][nt] = mfma16(aF[mt], bF[nt], acc[mt][nt]);
  }

  bf16_t* S = states + (size_t)wid * (HD * DSTATE);
  const int cr = (lane >> 4) * 4;
  const int cc = lane & 15;
#pragma unroll
  for (int mt = 0; mt < 4; ++mt)
#pragma unroll
    for (int nt = 0; nt < 2; ++nt) {
      int n = (w*2 + nt)*16 + cc;
#pragma unroll
      for (int r = 0; r < 4; ++r) {
        int p = mt*16 + cr + r;
        S[(size_t)p*DSTATE + n] = (bf16_t)acc[mt][nt][r];
      }
    }
}

// ---------------- inter-chunk scan over 32 chunks (in-place: states -> prevs) ----------------
__global__ __launch_bounds__(256)
void scan_kernel(bf16_t* __restrict__ sp, const float* __restrict__ cdec) {
  const size_t gid = (size_t)blockIdx.x * 256 + threadIdx.x;
  const int n = gid & 127;
  const int p = (gid >> 7) & 63;
  const int h = (gid >> 13) & 63;
  const int b = (int)(gid >> 19);
  float prev = 0.f;
  const size_t pn = (size_t)p * 128 + n;
  for (int c = 0; c < 32; ++c) {
    const int wid = (b*32 + c)*64 + h;
    const size_t idx = (size_t)wid * 8192 + pn;
    float s = (float)sp[idx];
    sp[idx] = (bf16_t)prev;
    prev = cdec[wid] * prev + s;
  }
}

// ---------------- per-chunk Y: inter + intra + D*x (in-place over x) ----------------
__global__ __launch_bounds__(256)
void ssd_y_kernel(bf16_t* __restrict__ xy, const bf16_t* __restrict__ Bm,
                  const bf16_t* __restrict__ Cm, const bf16_t* __restrict__ prevs,
                  const float* __restrict__ dt_s, const float* __restrict__ dAcs,
                  const float* __restrict__ Dvec) {
  __shared__ bf16_t sG[16384];
  __shared__ bf16_t sDtx[8192];
  __shared__ float sDA[128];
  __shared__ float sEA[128];
  __shared__ float sDt[128];

  const int wid = blockIdx.x;
  const int h = wid & 63;
  const int bc = wid >> 6;
  const int tid = threadIdx.x;
  const int lane = tid & 63;
  const int w = tid >> 6;
  const long tok0 = (long)bc * 128;
  const size_t dbase = (size_t)wid * 128;

  if (tid < 128) {
    float v = dAcs[dbase + tid];
    sDA[tid] = v;
    sEA[tid] = __expf(v);
  } else {
    sDt[tid - 128] = dt_s[dbase + tid - 128];
  }
  __syncthreads();

  {
    const int jj0 = tid >> 3;
    const int pg = (tid & 7) * 8;
#pragma unroll
    for (int t = 0; t < 4; ++t) {
      int j = t*32 + jj0;
      bf16x8 xv = *(const bf16x8*)&xy[(tok0 + j)*(long)DINNER + h*64 + pg];
      float dtj = sDt[j];
      int kq = (j >> 5) * 4;
      int qe = ((j >> 3) & 3) * 16;
      int e = j & 7;
#pragma unroll
      for (int i = 0; i < 8; ++i) {
        int p = pg + i;
        sDtx[((kq + (p>>4))*64 + qe + (p&15))*8 + e] = (bf16_t)((float)xv[i]*dtj);
      }
    }
  }

  const int arow = (w*2)*16 + (lane & 15);
  const int koff = (lane >> 4) * 8;
  bf16x8 aCm[2][4];
#pragma unroll
  for (int mi = 0; mi < 2; ++mi)
#pragma unroll
    for (int kt = 0; kt < 4; ++kt)
      aCm[mi][kt] = *(const bf16x8*)&Cm[(tok0 + arow + mi*16)*(long)DSTATE + kt*32 + koff];

  const bf16_t* P = prevs + (size_t)wid * 8192;
  f32x4 accY[2][4] = {};
#pragma unroll
  for (int kt = 0; kt < 4; ++kt) {
    bf16x8 bP[4];
#pragma unroll
    for (int ni = 0; ni < 4; ++ni)
      bP[ni] = *(const bf16x8*)&P[(size_t)(ni*16 + (lane & 15))*DSTATE + kt*32 + koff];
#pragma unroll
    for (int mi = 0; mi < 2; ++mi)
#pragma unroll
      for (int ni = 0; ni < 4; ++ni)
        accY[mi][ni] = mfma16(aCm[mi][kt], bP[ni], accY[mi][ni]);
  }
  const int cr = (lane >> 4) * 4;
  const int cc = lane & 15;
#pragma unroll
  for (int mi = 0; mi < 2; ++mi)
#pragma unroll
    for (int r = 0; r < 4; ++r) {
      float e = sEA[(w*2 + mi)*16 + cr + r];
#pragma unroll
      for (int ni = 0; ni < 4; ++ni) accY[mi][ni][r] *= e;
    }

  f32x4 accS[2][8] = {};
#pragma unroll
  for (int kt = 0; kt < 4; ++kt) {
    bf16x8 bB[8];
#pragma unroll
    for (int nt = 0; nt < 8; ++nt)
      bB[nt] = *(const bf16x8*)&Bm[(tok0 + nt*16 + (lane & 15))*(long)DSTATE + kt*32 + koff];
#pragma unroll
    for (int mi = 0; mi < 2; ++mi)
#pragma unroll
      for (int nt = 0; nt < 8; ++nt)
        accS[mi][nt] = mfma16(aCm[mi][kt], bB[nt], accS[mi][nt]);
  }

#pragma unroll
  for (int mi = 0; mi < 2; ++mi)
#pragma unroll
    for (int nt = 0; nt < 8; ++nt)
#pragma unroll
      for (int r = 0; r < 4; ++r) {
        int i = (w*2 + mi)*16 + cr + r;
        int j = nt*16 + cc;
        float g = (i >= j) ? accS[mi][nt][r] * __expf(sDA[i] - sDA[j]) : 0.f;
        sG[(((j>>5)*8 + (i>>4))*64 + ((j>>3)&3)*16 + (i&15))*8 + (j&7)] = (bf16_t)g;
      }
  __syncthreads();

#pragma unroll
  for (int kt = 0; kt < 4; ++kt) {
    bf16x8 aG[2], bD[4];
#pragma unroll
    for (int mi = 0; mi < 2; ++mi) aG[mi] = *(const bf16x8*)&sG[((kt*8 + w*2 + mi)*64 + lane)*8];
#pragma unroll
    for (int ni = 0; ni < 4; ++ni) bD[ni] = *(const bf16x8*)&sDtx[((kt*4 + ni)*64 + lane)*8];
#pragma unroll
    for (int mi = 0; mi < 2; ++mi)
#pragma unroll
      for (int ni = 0; ni < 4; ++ni)
        accY[mi][ni] = mfma16(aG[mi], bD[ni], accY[mi][ni]);
  }

  const float Dh = Dvec[h];
#pragma unroll
  for (int mi = 0; mi < 2; ++mi)
#pragma unroll
    for (int ni = 0; ni < 4; ++ni)
#pragma unroll
      for (int r = 0; r < 4; ++r) {
        long tokr = tok0 + (w*2 + mi)*16 + cr + r;
        int p = ni*16 + cc;
        long idx = tokr * DINNER + h*64 + p;
        float xv = (float)xy[idx];
        xy[idx] = (bf16_t)(accY[mi][ni][r] + Dh * xv);
      }
}

// ---------------- gating + RMS norm ----------------
__global__ __launch_bounds__(256)
void gate_kernel(const bf16_t* __restrict__ y, const bf16_t* __restrict__ z,
                 const float* __restrict__ norm_w, bf16_t* __restrict__ yn) {
  const int tok = blockIdx.x;
  const int tid = threadIdx.x;
  const int lane = tid & 63;
  const int w = tid >> 6;
  const bf16_t* yrow = y + (size_t)tok * DINNER;
  const bf16_t* zrow = z + (size_t)tok * DINNER;
  float local[16];
  float ss = 0.f;
#pragma unroll
  for (int v = 0; v < 2; ++v) {
    int col = tid*16 + v*8;
    bf16x8 yv = *(const bf16x8*)&yrow[col];
    bf16x8 zv = *(const bf16x8*)&zrow[col];
#pragma unroll
    for (int i = 0; i < 8; ++i) {
      float zf = (float)zv[i];
      float g = zf / (1.f + __expf(-zf));
      float t = (float)yv[i] * g;
      local[v*8 + i] = t;
      ss += t*t;
    }
  }
#pragma unroll
  for (int off = 32; off > 0; off >>= 1) ss += __shfl_xor(ss, off);
  __shared__ float red[4];
  if (lane == 0) red[w] = ss;
  __syncthreads();
  float rms = rsqrtf((red[0]+red[1]+red[2]+red[3]) * (1.f/DINNER) + 1e-5f);
  bf16_t* orow = yn + (size_t)tok * DINNER;
#pragma unroll
  for (int v = 0; v < 2; ++v) {
    int col = tid*16 + v*8;
    bf16x8 o;
#pragma unroll
    for (int i = 0; i < 8; ++i) o[i] = (bf16_t)(local[v*8+i] * rms * norm_w[col+i]);
    *(bf16x8*)&orow[col] = o;
  }
}

// ---------------- launch ----------------
extern "C" void kernel_launch(void* const* d_in, const int* in_sizes, int n_in,
                              void* d_out, int out_size, void* d_ws, size_t ws_size,
                              hipStream_t stream) {
  const float* hidden  = (const float*)d_in[0];
  const float* W_in    = (const float*)d_in[1];
  const float* conv_w  = (const float*)d_in[2];
  const float* conv_b  = (const float*)d_in[3];
  const float* Avec    = (const float*)d_in[4];
  const float* Dvec    = (const float*)d_in[5];
  const float* dt_bias = (const float*)d_in[6];
  const float* norm_w  = (const float*)d_in[7];
  const float* W_out   = (const float*)d_in[8];

  char* ws = (char*)d_ws;
  size_t off = 0;
  auto take = [&](size_t bytes) -> char* {
    char* p = ws + off;
    off += (bytes + 255) & ~(size_t)255;
    return p;
  };
  bf16_t* R1    = (bf16_t*)take((size_t)NBC * NH * HD * DSTATE * 2);  // Xb -> states -> ynbuf
  bf16_t* WinT  = (bf16_t*)take((size_t)WINT_ROWS * DMODEL * 2);      // later WoutT
  bf16_t* xbc   = (bf16_t*)take((size_t)TOK * XBCN * 2);              // Xlo lives here first
  bf16_t* xconv = (bf16_t*)take((size_t)TOK * DINNER * 2);            // y in-place
  bf16_t* Bmat  = (bf16_t*)take((size_t)TOK * DSTATE * 2);
  bf16_t* Cmat  = (bf16_t*)take((size_t)TOK * DSTATE * 2);
  float*  dtraw = (float*)take((size_t)TOK * NH * 4);
  float*  dt_s  = (float*)take((size_t)TOK * NH * 4);
  float*  dAcs  = (float*)take((size_t)TOK * NH * 4);
  float*  cdec  = (float*)take((size_t)NBC * NH * 4);
  bf16_t* Wdth  = (bf16_t*)take((size_t)NH * DMODEL * 2);
  bf16_t* Wdtl  = (bf16_t*)take((size_t)NH * DMODEL * 2);
  if (off > ws_size) return;

  bf16_t* Xb      = R1;
  bf16_t* Xlo     = xbc;               // dead before xbc-gemm writes
  bf16_t* statesB = R1;
  bf16_t* ynbuf   = R1;
  bf16_t* WoutT   = WinT;
  bf16_t* zbuf    = (bf16_t*)d_out;    // z as bf16 in d_out
  float*  out     = (float*)d_out;

  cast_split_kernel<<<(TOK*DMODEL)/2048, 256, 0, stream>>>(hidden, Xb, Xlo, (size_t)TOK*DMODEL);
  wdt_split_kernel<<<DMODEL/256, 256, 0, stream>>>(W_in, Wdth, Wdtl);
  dt_mfma_kernel<<<TOK/32, 512, 0, stream>>>(Xb, Xlo, Wdth, Wdtl, dtraw);
  transpose_cast_kernel<<<dim3(WINT_ROWS/32, DMODEL/32), 256, 0, stream>>>(W_in, WinT, DMODEL, 8512, WINT_ROWS);
  // fused in-proj: cols [0,4096) -> zbuf, [4096,8448) -> xbc
  gemm256<bf16_t><<<(TOK/256)*(WINT_ROWS/256), 512, 0, stream>>>(
      Xb, WinT, zbuf, xbc, TOK, WINT_ROWS, DMODEL, DINNER, WINT_ROWS/256);
  transpose_cast_kernel<<<dim3(DMODEL/32, DINNER/32), 256, 0, stream>>>(W_out, WoutT, DINNER, DMODEL, DMODEL);
  conv_kernel<<<dim3(XBCN/256, TOK/8), 256, 0, stream>>>(xbc, conv_w, conv_b, xconv, Bmat, Cmat);
  dt_scan_kernel<<<(NBC*NH)/4, 256, 0, stream>>>(dtraw, dt_bias, Avec, dt_s, dAcs, cdec);
  states_kernel<<<NBC*NH, 256, 0, stream>>>(xconv, Bmat, dt_s, dAcs, statesB);
  scan_kernel<<<(NBC*NH*HD*DSTATE)/(32*256), 256, 0, stream>>>(statesB, cdec);
  ssd_y_kernel<<<NBC*NH, 256, 0, stream>>>(xconv, Bmat, Cmat, statesB, dt_s, dAcs, Dvec);
  gate_kernel<<<TOK, 256, 0, stream>>>(xconv, zbuf, norm_w, ynbuf);
  // out-proj
  gemm256<float><<<(TOK/256)*(DMODEL/256), 512, 0, stream>>>(
      ynbuf, WoutT, out, out, TOK, DMODEL, DINNER, DMODEL, DMODEL/256);
}